// Round 3
// baseline (786.644 us; speedup 1.0000x reference)
//
#include <hip/hip_runtime.h>
#include <math.h>

#define T_SEQ 2048
#define BATCH 4
#define E_DIM 2048
#define NHEAD 16
#define HDIM 128
#define RMS_EPS 1.1920929e-07f
#define NQT (T_SEQ / 128)          // 16 q-tiles of 128

typedef unsigned short u16;
typedef __attribute__((ext_vector_type(8))) unsigned short u16x8;
typedef __attribute__((ext_vector_type(8))) short bf16x8;
typedef __attribute__((ext_vector_type(4))) float f32x4;

typedef const __attribute__((address_space(1))) unsigned int g_u32;
typedef __attribute__((address_space(3))) unsigned int l_u32;

static __device__ __forceinline__ u16 f2b(float f) {
  unsigned int u = __builtin_bit_cast(unsigned int, f);
  u += 0x7fffu + ((u >> 16) & 1u);
  return (u16)(u >> 16);
}
static __device__ __forceinline__ float b2f(u16 v) {
  return __builtin_bit_cast(float, ((unsigned int)v) << 16);
}

// ---------------- fp32 -> bf16 convert (x only) ----------------
__global__ __launch_bounds__(256) void convert_f32_bf16(
    const float* __restrict__ src, u16* __restrict__ dst, int n) {
  int i = (blockIdx.x * 256 + threadIdx.x) * 4;
  if (i >= n) return;
  float4 v = *reinterpret_cast<const float4*>(src + i);
  ushort4 o;
  o.x = f2b(v.x); o.y = f2b(v.y); o.z = f2b(v.z); o.w = f2b(v.w);
  *reinterpret_cast<ushort4*>(dst + i) = o;
}

// ---------------- fused fp32->bf16 convert + transpose: Wt[n][k]=W[k][n] ----
__global__ __launch_bounds__(256) void convt_w_k(
    const float* __restrict__ W, u16* __restrict__ Wt) {
  __shared__ u16 tile[64][72];
  int c0 = blockIdx.x * 64;
  int r0 = blockIdx.y * 64;
  int tid = threadIdx.x;
  int lrow = tid >> 2;
  int lcol = (tid & 3) * 16;
#pragma unroll
  for (int i = 0; i < 4; ++i) {
    float4 v = *reinterpret_cast<const float4*>(
        W + (long long)(r0 + lrow) * E_DIM + c0 + lcol + i * 4);
    tile[lrow][lcol + i * 4 + 0] = f2b(v.x);
    tile[lrow][lcol + i * 4 + 1] = f2b(v.y);
    tile[lrow][lcol + i * 4 + 2] = f2b(v.z);
    tile[lrow][lcol + i * 4 + 3] = f2b(v.w);
  }
  __syncthreads();
  int wrow = tid >> 2;
  int wcol = (tid & 3) * 16;
  u16 o[16];
#pragma unroll
  for (int i = 0; i < 16; ++i) o[i] = tile[wcol + i][wrow];
  u16* dst = Wt + (long long)(c0 + wrow) * E_DIM + r0 + wcol;
  *reinterpret_cast<u16x8*>(dst)     = *reinterpret_cast<u16x8*>(&o[0]);
  *reinterpret_cast<u16x8*>(dst + 8) = *reinterpret_cast<u16x8*>(&o[8]);
}

// ---------------- rope tables (double precision trig) ----------------
__global__ __launch_bounds__(256) void rope_tables_k(
    float* __restrict__ cost, float* __restrict__ sint) {
  int idx = blockIdx.x * 256 + threadIdx.x;
  int i = idx & 63, t = idx >> 6;
  double inv = pow(10000.0, -(double)i / 64.0);
  double ang = (double)t * inv;
  cost[idx] = (float)cos(ang);
  sint[idx] = (float)sin(ang);
}

// ---------------- fused rope + rmsnorm (in-place on bf16 Q and K) ----------
__global__ __launch_bounds__(256) void rope_rms_k(
    u16* __restrict__ Qb, u16* __restrict__ Kb, const float* __restrict__ cost,
    const float* __restrict__ sint) {
  int half = gridDim.x >> 1;
  int isK = blockIdx.x >= half;
  u16* qk = isK ? Kb : Qb;
  float outscale = isK ? 1.0f : 0.08838834764831845f;  // fold 1/sqrt(128) into Q
  int wave = threadIdx.x >> 6;
  int lane = threadIdx.x & 63;
  long long row = (long long)(blockIdx.x - (isK ? half : 0)) * 4 + wave;
  int th = (int)(row >> 4);
  int t = th & (T_SEQ - 1);
  u16* p = qk + row * HDIM;
  float x1 = b2f(p[lane]);
  float x2 = b2f(p[lane + 64]);
  float c = cost[t * 64 + lane];
  float s = sint[t * 64 + lane];
  float o1 = x1 * c - x2 * s;
  float o2 = x1 * s + x2 * c;
  float ss = o1 * o1 + o2 * o2;
#pragma unroll
  for (int m = 32; m >= 1; m >>= 1) ss += __shfl_xor(ss, m, 64);
  float r = rsqrtf(ss * (1.0f / 128.0f) + RMS_EPS) * outscale;
  p[lane] = f2b(o1 * r);
  p[lane + 64] = f2b(o2 * r);
}

// ---------------- V transpose: [B,T,H,D] -> per (b,h): [D][T] ----------------
__global__ __launch_bounds__(256) void transpose_v_k(
    const u16* __restrict__ V, u16* __restrict__ Vt) {
  __shared__ u16 tile[64][72];
  int t0 = blockIdx.x * 64, d0 = blockIdx.y * 64;
  int bh = blockIdx.z;
  int b = bh >> 4, h = bh & 15;
  int tid = threadIdx.x;
  int lrow = tid >> 3;
  int lcol = (tid & 7) * 8;
#pragma unroll
  for (int pass = 0; pass < 2; ++pass) {
    int row = lrow + pass * 32;
    const u16* src = V + ((((long long)b * T_SEQ + t0 + row) * NHEAD + h) << 7) + d0 + lcol;
    *reinterpret_cast<u16x8*>(&tile[row][lcol]) = *reinterpret_cast<const u16x8*>(src);
  }
  __syncthreads();
#pragma unroll
  for (int pass = 0; pass < 2; ++pass) {
    int drow = (tid >> 3) + pass * 32;
    int tcol = (tid & 7) * 8;
    u16x8 o;
#pragma unroll
    for (int i = 0; i < 8; ++i) o[i] = tile[tcol + i][drow];
    u16* dst = Vt + ((long long)bh * HDIM + d0 + drow) * T_SEQ + t0 + tcol;
    *reinterpret_cast<u16x8*>(dst) = o;
  }
}

// ---------------- bf16 MFMA GEMM: 256x256 tile, pipelined 8-phase ----------
// C[M,N] = A[M,K] * Bt[N,K]^T.  512 threads = 8 waves (2M x 4N), each wave
// owns 128x64 output (8x4 frags of 16x16, mfma_f32_16x16x32_bf16, BK=64).
// LDS: 2 x (A 256x64 + B 256x64) bf16 = 128 KiB, double buffered.
// Pipelined reads: phase p issues the ds_reads for phase p+1; MFMA of p
// consumes fragments read at p-1 -> LDS drain overlaps MFMA (compiler emits
// counted lgkmcnt leaving the new reads in flight).  2-tile unrolled body so
// register sets (aX/aY, bU/bV) and buffers are static.  vmcnt(6)@p2
// publishes B(t+1) (for p3's bB prefetch), vmcnt(4)@p3 publishes A(t+1)
// (for p4's aA prefetch); tail iteration tightens to 4/0.
__global__ __launch_bounds__(512, 2) void gemm_bt_k(
    const u16* __restrict__ A,
    const u16* __restrict__ Bt0, const u16* __restrict__ Bt1, const u16* __restrict__ Bt2,
    u16* __restrict__ C0, u16* __restrict__ C1, u16* __restrict__ C2,
    float* __restrict__ Cf, int M, int N, int K) {
  // ---- XCD-aware tile remap (bijective; gx=8, gy=32, gz in {1,3}) ----
  int lin = blockIdx.x + (blockIdx.y << 3) + (blockIdx.z << 8);
  int kx = lin & 7, ii = lin >> 3;
  int by = ((kx >> 1) << 3) + (ii & 7);   // m-tile: 8-chunk per XCD-pair class
  int bx, bz;
  if (gridDim.z == 3) {
    int u = (kx & 1) * 12 + (ii >> 3);    // 24 (n,z) tiles split in two 12-slices
    bx = u & 7; bz = u >> 3;
  } else {
    bx = ((kx & 1) << 2) + (ii >> 3);     // 8 n-tiles split in two 4-slices
    bz = 0;
  }
  const u16* Bt = bz == 0 ? Bt0 : (bz == 1 ? Bt1 : Bt2);
  u16* C = bz == 0 ? C0 : (bz == 1 ? C1 : C2);

  __shared__ u16 As[2][256 * 64];
  __shared__ u16 Bs[2][256 * 64];
  u16* A0 = As[0]; u16* A1 = As[1];
  u16* B0 = Bs[0]; u16* B1 = Bs[1];
  const int tid = threadIdx.x;
  const int lane = tid & 63, wave = tid >> 6;
  const int wm = wave >> 2, wn = wave & 3;   // 2 x 4 wave grid
  const int m0 = by * 256, n0 = bx * 256;
  const int lr = lane & 15, lq = lane >> 4, l7 = lane & 7;
  const int NT = K >> 6;

  // Staging halves: A half h = rows with bit6==h; B half h = rows bit5==h.
  int rowA[2][2], rowB[2][2];
  const u16* gA[2][2];
  const u16* gB[2][2];
#pragma unroll
  for (int l = 0; l < 2; ++l) {
    int rihb = l * 64 + wave * 8;
#pragma unroll
    for (int h = 0; h < 2; ++h) {
      int ra = ((rihb >> 6) << 7) + h * 64 + (rihb & 63);
      int rb = ((rihb >> 5) << 6) + h * 32 + (rihb & 31);
      rowA[h][l] = ra;
      rowB[h][l] = rb;
      int rA = ra + (lane >> 3);
      int rB = rb + (lane >> 3);
      // inverse-swizzled global source: LDS[r][c] <- G[r][c ^ (r&7)]
      gA[h][l] = A + (long long)(m0 + rA) * K + ((l7 ^ (rA & 7)) * 8);
      gB[h][l] = Bt + (long long)(n0 + rB) * K + ((l7 ^ (rB & 7)) * 8);
    }
  }

  f32x4 acc[8][4] = {};
  bf16x8 aX[2][2], aY[2][2], bU[4][2], bV[4][2];

#define GLDS(gp, lp) \
  __builtin_amdgcn_global_load_lds((g_u32*)(gp), (l_u32*)(lp), 16, 0, 0)
#define STG_A(bufp, h, off) do {                                              \
    GLDS(gA[h][0] + (off), (bufp) + rowA[h][0] * 64);                         \
    GLDS(gA[h][1] + (off), (bufp) + rowA[h][1] * 64); } while (0)
#define STG_B(bufp, h, off) do {                                              \
    GLDS(gB[h][0] + (off), (bufp) + rowB[h][0] * 64);                         \
    GLDS(gB[h][1] + (off), (bufp) + rowB[h][1] * 64); } while (0)
#define LDSA(dst, buf, mtb)                                                   \
  _Pragma("unroll") for (int mi = 0; mi < 2; ++mi)                            \
  _Pragma("unroll") for (int ks = 0; ks < 2; ++ks)                            \
    dst[mi][ks] = *reinterpret_cast<const bf16x8*>(                           \
        (buf) + (wm * 128 + ((mtb) + mi) * 16 + lr) * 64 +                    \
        ((((ks) << 2) + lq) ^ l7) * 8);
#define LDSB(dst, buf)                                                        \
  _Pragma("unroll") for (int ni = 0; ni < 4; ++ni)                            \
  _Pragma("unroll") for (int ks = 0; ks < 2; ++ks)                            \
    dst[ni][ks] = *reinterpret_cast<const bf16x8*>(                           \
        (buf) + (wn * 64 + (ni) * 16 + lr) * 64 +                             \
        ((((ks) << 2) + lq) ^ l7) * 8);
#define MFMA2(ph, a, b)                                                       \
  _Pragma("unroll") for (int mi = 0; mi < 2; ++mi)                            \
  _Pragma("unroll") for (int ni = 0; ni < 4; ++ni)                            \
  _Pragma("unroll") for (int ks = 0; ks < 2; ++ks)                            \
    acc[(ph) * 2 + mi][ni] = __builtin_amdgcn_mfma_f32_16x16x32_bf16(         \
        a[mi][ks], b[ni][ks], acc[(ph) * 2 + mi][ni], 0, 0, 0);
#define SB __builtin_amdgcn_sched_barrier(0)
#define BAR __builtin_amdgcn_s_barrier()
#define VMC(n) asm volatile("s_waitcnt vmcnt(" #n ")" ::: "memory")
#define PH_MID SB; BAR; SB; __builtin_amdgcn_s_setprio(1)
#define PH_END __builtin_amdgcn_s_setprio(0); SB; BAR; SB

  // prologue: tile0 (8 loads) + tile1 {B0,B1,A-h0} (6); vmcnt(6) completes
  // tile0, keeps 3 halves in flight; then prefetch first-phase fragments.
  GLDS(gB[0][0], B0 + rowB[0][0] * 64); GLDS(gB[0][1], B0 + rowB[0][1] * 64);
  GLDS(gB[1][0], B0 + rowB[1][0] * 64); GLDS(gB[1][1], B0 + rowB[1][1] * 64);
  GLDS(gA[0][0], A0 + rowA[0][0] * 64); GLDS(gA[0][1], A0 + rowA[0][1] * 64);
  GLDS(gA[1][0], A0 + rowA[1][0] * 64); GLDS(gA[1][1], A0 + rowA[1][1] * 64);
  GLDS(gB[0][0] + 64, B1 + rowB[0][0] * 64); GLDS(gB[0][1] + 64, B1 + rowB[0][1] * 64);
  GLDS(gB[1][0] + 64, B1 + rowB[1][0] * 64); GLDS(gB[1][1] + 64, B1 + rowB[1][1] * 64);
  GLDS(gA[0][0] + 64, A1 + rowA[0][0] * 64); GLDS(gA[0][1] + 64, A1 + rowA[0][1] * 64);
  VMC(6);
  BAR; SB;
  LDSB(bU, B0);
  LDSA(aX, A0, 0);
  SB;

#pragma unroll 1
  for (int t = 0; t < NT; t += 2) {
    const bool nl = (t + 2 < NT);       // not last iteration
    // ===== tile t (reads buf0) =====
    // p1: prefetch a(mt2,3); stage A(t+1,h1)->buf1
    LDSA(aY, A0, 2);
    STG_A(A1, 1, 64);
    PH_MID; MFMA2(0, aX, bU); PH_END;
    // p2: prefetch a(mt4,5); stage B(t+2,h0)->buf0; publish B(t+1)
    LDSA(aX, A0, 4);
    if (nl) { STG_B(B0, 0, 128); VMC(6); } else { VMC(4); }
    PH_MID; MFMA2(1, aY, bU); PH_END;
    // p3: prefetch a(mt6,7) + bV = B(t+1); stage B(t+2,h1); publish A(t+1)
    LDSA(aY, A0, 6);
    LDSB(bV, B1);
    if (nl) { STG_B(B0, 1, 128); VMC(4); } else { VMC(0); }
    PH_MID; MFMA2(2, aX, bU); PH_END;
    // p4: prefetch a(t+1, mt0,1); stage A(t+2,h0)->buf0
    LDSA(aX, A1, 0);
    if (nl) STG_A(A0, 0, 128);
    PH_MID; MFMA2(3, aY, bU); PH_END;
    // ===== tile t+1 (reads buf1) =====
    // p1': prefetch a(mt2,3); stage A(t+2,h1)->buf0
    LDSA(aY, A1, 2);
    if (nl) STG_A(A0, 1, 128);
    PH_MID; MFMA2(0, aX, bV); PH_END;
    // p2': prefetch a(mt4,5); stage B(t+3,h0)->buf1; publish B(t+2)
    LDSA(aX, A1, 4);
    if (nl) { STG_B(B1, 0, 192); VMC(6); }
    PH_MID; MFMA2(1, aY, bV); PH_END;
    // p3': prefetch a(mt6,7) + bU = B(t+2); stage B(t+3,h1); publish A(t+2)
    LDSA(aY, A1, 6);
    LDSB(bU, B0);
    if (nl) { STG_B(B1, 1, 192); VMC(4); }
    PH_MID; MFMA2(2, aX, bV); PH_END;
    // p4': prefetch a(t+2, mt0,1); stage A(t+3,h0)->buf1
    LDSA(aX, A0, 0);
    if (nl) STG_A(A1, 0, 192);
    PH_MID; MFMA2(3, aY, bV); PH_END;
    // advance 2 K-tiles
#pragma unroll
    for (int l = 0; l < 2; ++l)
#pragma unroll
      for (int h = 0; h < 2; ++h) { gA[h][l] += 128; gB[h][l] += 128; }
  }
#undef LDSA
#undef LDSB
#undef MFMA2
#undef STG_A
#undef STG_B
#undef GLDS
#undef PH_MID
#undef PH_END

  // epilogue: C col = lane&15, row = (lane>>4)*4 + reg   (16x16 C/D layout)
#pragma unroll
  for (int mt = 0; mt < 8; ++mt)
#pragma unroll
    for (int nt = 0; nt < 4; ++nt) {
      long long col = n0 + wn * 64 + nt * 16 + lr;
#pragma unroll
      for (int r = 0; r < 4; ++r) {
        long long row = m0 + wm * 128 + mt * 16 + lq * 4 + r;
        float v = acc[mt][nt][r];
        if (Cf) Cf[row * N + col] = v;
        else C[row * N + col] = f2b(v);
      }
    }
}

// ---------------- causal flash attention v3 (XCD-remapped grid) ----------
__global__ __launch_bounds__(256, 3) void attn_k(
    const u16* __restrict__ Q, const u16* __restrict__ K,
    const u16* __restrict__ Vt, u16* __restrict__ Y) {
  __shared__ u16 Ks[64 * 128];        // row=key, 16 chunks/row, slot=(g+key)&15
  __shared__ u16 Vs[128 * 64];        // row=d, 8 chunks/row, slot=(g+d)&7
  __shared__ u16 Ps[4][32 * 72];      // per-wave P [q][key], pad 64->72
  __shared__ float Al[4][32];         // per-wave alpha / l broadcast
  // XCD remap (hw xcd = lin%8; gx = NQT/2 = 8): XCD k owns bh in [8k, 8k+8)
  int lin = blockIdx.x + (blockIdx.y << 3);
  int pair = (lin >> 6);              // 0..NQT/2-1
  int bh = ((lin & 7) << 3) + ((lin >> 3) & 7);
  int b = bh >> 4, h = bh & 15;
  int tid = threadIdx.x, lane = tid & 63, wave = tid >> 6;
  int lr = lane & 15, lq = lane >> 4;

  const u16* kp[4];
  const u16* vp[4];
#pragma unroll
  for (int p = 0; p < 4; ++p) {
    int c = p * 256 + wave * 64 + lane;
    int key = c >> 4, sk = c & 15, gk = (sk - key) & 15;
    kp[p] = K + (((long long)b * T_SEQ + key) * NHEAD + h) * HDIM + gk * 8;
    int d = c >> 3, sv = c & 7, gv = (sv - d) & 7;
    vp[p] = Vt + ((long long)bh * HDIM + d) * T_SEQ + gv * 8;
  }

#pragma unroll 1
  for (int phase = 0; phase < 2; ++phase) {
    int qt = phase == 0 ? (NQT - 1 - pair) : pair;
    int qbase = qt * 128 + wave * 32;

    bf16x8 aq[2][4];
#pragma unroll
    for (int n2 = 0; n2 < 2; ++n2) {
      const u16* qp = Q + (((long long)b * T_SEQ + qbase + n2 * 16 + lr) * NHEAD + h) * HDIM;
#pragma unroll
      for (int kt = 0; kt < 4; ++kt)
        aq[n2][kt] = *reinterpret_cast<const bf16x8*>(qp + kt * 32 + lq * 8);
    }

    float m_s[2], l_s[2];
#pragma unroll
    for (int n2 = 0; n2 < 2; ++n2) { m_s[n2] = -INFINITY; l_s[n2] = 0.f; }
    f32x4 o[2][8] = {};

    int niter = 2 * qt + 2;
    for (int j = 0; j < niter; ++j) {
      __syncthreads();
#pragma unroll
      for (int p = 0; p < 4; ++p) {
        __builtin_amdgcn_global_load_lds(
            (g_u32*)(kp[p] + (long long)j * 64 * NHEAD * HDIM),
            (l_u32*)(Ks + p * 2048 + wave * 512), 16, 0, 0);
        __builtin_amdgcn_global_load_lds(
            (g_u32*)(vp[p] + j * 64),
            (l_u32*)(Vs + p * 2048 + wave * 512), 16, 0, 0);
      }
      __syncthreads();

      f32x4 s[4][2];
#pragma unroll
      for (int mt = 0; mt < 4; ++mt) {
        int key = mt * 16 + lr;
        bf16x8 ak[4];
#pragma unroll
        for (int kt = 0; kt < 4; ++kt) {
          int slot = (kt * 4 + lq + key) & 15;
          ak[kt] = *reinterpret_cast<const bf16x8*>(&Ks[key * 128 + slot * 8]);
        }
#pragma unroll
        for (int n2 = 0; n2 < 2; ++n2) {
          f32x4 acc = {};
#pragma unroll
          for (int kt = 0; kt < 4; ++kt)
            acc = __builtin_amdgcn_mfma_f32_16x16x32_bf16(ak[kt], aq[n2][kt], acc, 0, 0, 0);
          s[mt][n2] = acc;
        }
      }

      if (j >= 2 * qt) {
#pragma unroll
        for (int mt = 0; mt < 4; ++mt)
#pragma unroll
          for (int n2 = 0; n2 < 2; ++n2) {
            int q = qbase + n2 * 16 + lr;
#pragma unroll
            for (int r = 0; r < 4; ++r) {
              int key = j * 64 + mt * 16 + lq * 4 + r;
              if (key > q) s[mt][n2][r] = -INFINITY;
            }
          }
      }

      float alpha[2];
#pragma unroll
      for (int n2 = 0; n2 < 2; ++n2) {
        float mx = s[0][n2][0];
#pragma unroll
        for (int mt = 0; mt < 4; ++mt)
#pragma unroll
          for (int r = 0; r < 4; ++r) mx = fmaxf(mx, s[mt][n2][r]);
        mx = fmaxf(mx, __shfl_xor(mx, 16, 64));
        mx = fmaxf(mx, __shfl_xor(mx, 32, 64));
        float mn = fmaxf(m_s[n2], mx);
        alpha[n2] = __expf(m_s[n2] - mn);
        m_s[n2] = mn;
        float sum = 0.f;
        int q = n2 * 16 + lr;
#pragma unroll
        for (int mt = 0; mt < 4; ++mt) {
          ushort4 pk;
          float p0 = __expf(s[mt][n2][0] - mn);
          float p1 = __expf(s[mt][n2][1] - mn);
          float p2 = __expf(s[mt][n2][2] - mn);
          float p3 = __expf(s[mt][n2][3] - mn);
          sum += (p0 + p1) + (p2 + p3);
          pk.x = f2b(p0); pk.y = f2b(p1); pk.z = f2b(p2); pk.w = f2b(p3);
          *reinterpret_cast<ushort4*>(&Ps[wave][q * 72 + mt * 16 + lq * 4]) = pk;
        }
        sum += __shfl_xor(sum, 16, 64);
        sum += __shfl_xor(sum, 32, 64);
        l_s[n2] = l_s[n2] * alpha[n2] + sum;
      }

      if (lq == 0) {
        Al[wave][lr] = alpha[0];
        Al[wave][16 + lr] = alpha[1];
      }
#pragma unroll
      for (int q2 = 0; q2 < 2; ++q2) {
        f32x4 av = *reinterpret_cast<const f32x4*>(&Al[wave][q2 * 16 + lq * 4]);
#pragma unroll
        for (int r = 0; r < 4; ++r)
#pragma unroll
          for (int dt = 0; dt < 8; ++dt) o[q2][dt][r] *= av[r];
      }

#pragma unroll
      for (int kh = 0; kh < 2; ++kh) {
        bf16x8 ap[2];
#pragma unroll
        for (int q2 = 0; q2 < 2; ++q2)
          ap[q2] = *reinterpret_cast<const bf16x8*>(
              &Ps[wave][(q2 * 16 + lr) * 72 + kh * 32 + lq * 8]);
#pragma unroll
        for (int dt = 0; dt < 8; ++dt) {
          int d = dt * 16 + lr;
          int slot = (kh * 4 + lq + d) & 7;
          bf16x8 bv = *reinterpret_cast<const bf16x8*>(&Vs[d * 64 + slot * 8]);
#pragma unroll
          for (int q2 = 0; q2 < 2; ++q2)
            o[q2][dt] = __builtin_amdgcn_mfma_f32_16x16x32_bf16(ap[q2], bv, o[q2][dt], 0, 0, 0);
        }
      }
    }

    if (lq == 0) {
      Al[wave][lr] = l_s[0];
      Al[wave][16 + lr] = l_s[1];
    }
#pragma unroll
    for (int q2 = 0; q2 < 2; ++q2) {
      f32x4 lv = *reinterpret_cast<const f32x4*>(&Al[wave][q2 * 16 + lq * 4]);
#pragma unroll
      for (int r = 0; r < 4; ++r) {
        float inv = 1.0f / lv[r];
        int q = qbase + q2 * 16 + lq * 4 + r;
        u16* yp = Y + (((long long)b * T_SEQ + q) * NHEAD + h) * HDIM;
#pragma unroll
        for (int dt = 0; dt < 8; ++dt)
          yp[dt * 16 + lr] = f2b(o[q2][dt][r] * inv);
      }
    }
  }
}

extern "C" void kernel_launch(void* const* d_in, const int* in_sizes, int n_in,
                              void* d_out, int out_size, void* d_ws, size_t ws_size,
                              hipStream_t stream) {
  (void)in_sizes; (void)n_in; (void)out_size; (void)ws_size;
  const float* x  = (const float*)d_in[0];
  const float* wq = (const float*)d_in[1];
  const float* wk = (const float*)d_in[2];
  const float* wv = (const float*)d_in[3];
  const float* wo = (const float*)d_in[4];
  float* out = (float*)d_out;

  char* ws = (char*)d_ws;
  size_t off = 0;
  auto alloc = [&](size_t bytes) {
    char* p = ws + off;
    off += (bytes + 255) & ~(size_t)255;
    return p;
  };
  const size_t NTOK = (size_t)BATCH * T_SEQ;
  const size_t XE = NTOK * E_DIM;
  const size_t WE = (size_t)E_DIM * E_DIM;

  u16* xb  = (u16*)alloc(XE * 2);
  u16* wqt = (u16*)alloc(WE * 2);
  u16* wkt = (u16*)alloc(WE * 2);
  u16* wvt = (u16*)alloc(WE * 2);
  u16* wot = (u16*)alloc(WE * 2);
  u16* Qb  = (u16*)alloc(XE * 2);
  u16* Kb  = (u16*)alloc(XE * 2);
  u16* Vb  = (u16*)alloc(XE * 2);
  u16* Vt  = (u16*)alloc(XE * 2);
  u16* Yb  = (u16*)alloc(XE * 2);
  float* cost = (float*)alloc((size_t)T_SEQ * 64 * 4);
  float* sint = (float*)alloc((size_t)T_SEQ * 64 * 4);

  convert_f32_bf16<<<XE / 1024, 256, 0, stream>>>(x, xb, (int)XE);
  dim3 gw(E_DIM / 64, E_DIM / 64);
  convt_w_k<<<gw, 256, 0, stream>>>(wq, wqt);
  convt_w_k<<<gw, 256, 0, stream>>>(wk, wkt);
  convt_w_k<<<gw, 256, 0, stream>>>(wv, wvt);
  convt_w_k<<<gw, 256, 0, stream>>>(wo, wot);
  rope_tables_k<<<(T_SEQ * 64) / 256, 256, 0, stream>>>(cost, sint);

  dim3 gq(E_DIM / 256, NTOK / 256, 3);
  gemm_bt_k<<<gq, 512, 0, stream>>>(xb, wqt, wkt, wvt, Qb, Kb, Vb, nullptr,
                                    (int)NTOK, E_DIM, E_DIM);

  rope_rms_k<<<(unsigned)(NTOK * NHEAD / 4) * 2, 256, 0, stream>>>(Qb, Kb, cost, sint);

  dim3 gt(T_SEQ / 64, HDIM / 64, BATCH * NHEAD);
  transpose_v_k<<<gt, 256, 0, stream>>>(Vb, Vt);

  dim3 ga(NQT / 2, BATCH * NHEAD);
  attn_k<<<ga, 256, 0, stream>>>(Qb, Kb, Vt, Yb);

  dim3 go(E_DIM / 256, NTOK / 256, 1);
  gemm_bt_k<<<go, 512, 0, stream>>>(Yb, wot, wot, wot, nullptr, nullptr, nullptr, out,
                                    (int)NTOK, E_DIM, E_DIM);
}

// Round 4
// 628.467 us; speedup vs baseline: 1.2517x; 1.2517x over previous
//
#include <hip/hip_runtime.h>
#include <math.h>

#define T_SEQ 2048
#define BATCH 4
#define E_DIM 2048
#define NHEAD 16
#define HDIM 128
#define RMS_EPS 1.1920929e-07f
#define NQT (T_SEQ / 128)          // 16 q-tiles of 128

typedef unsigned short u16;
typedef __attribute__((ext_vector_type(8))) unsigned short u16x8;
typedef __attribute__((ext_vector_type(8))) short bf16x8;
typedef __attribute__((ext_vector_type(4))) float f32x4;

typedef const __attribute__((address_space(1))) unsigned int g_u32;
typedef __attribute__((address_space(3))) unsigned int l_u32;

static __device__ __forceinline__ u16 f2b(float f) {
  unsigned int u = __builtin_bit_cast(unsigned int, f);
  u += 0x7fffu + ((u >> 16) & 1u);
  return (u16)(u >> 16);
}
static __device__ __forceinline__ float b2f(u16 v) {
  return __builtin_bit_cast(float, ((unsigned int)v) << 16);
}

// ---------------- fp32 -> bf16 convert (x only) ----------------
__global__ __launch_bounds__(256) void convert_f32_bf16(
    const float* __restrict__ src, u16* __restrict__ dst, int n) {
  int i = (blockIdx.x * 256 + threadIdx.x) * 4;
  if (i >= n) return;
  float4 v = *reinterpret_cast<const float4*>(src + i);
  ushort4 o;
  o.x = f2b(v.x); o.y = f2b(v.y); o.z = f2b(v.z); o.w = f2b(v.w);
  *reinterpret_cast<ushort4*>(dst + i) = o;
}

// ---------------- fused fp32->bf16 convert + transpose: Wt[n][k]=W[k][n] ----
__global__ __launch_bounds__(256) void convt_w_k(
    const float* __restrict__ W, u16* __restrict__ Wt) {
  __shared__ u16 tile[64][72];
  int c0 = blockIdx.x * 64;
  int r0 = blockIdx.y * 64;
  int tid = threadIdx.x;
  int lrow = tid >> 2;
  int lcol = (tid & 3) * 16;
#pragma unroll
  for (int i = 0; i < 4; ++i) {
    float4 v = *reinterpret_cast<const float4*>(
        W + (long long)(r0 + lrow) * E_DIM + c0 + lcol + i * 4);
    tile[lrow][lcol + i * 4 + 0] = f2b(v.x);
    tile[lrow][lcol + i * 4 + 1] = f2b(v.y);
    tile[lrow][lcol + i * 4 + 2] = f2b(v.z);
    tile[lrow][lcol + i * 4 + 3] = f2b(v.w);
  }
  __syncthreads();
  int wrow = tid >> 2;
  int wcol = (tid & 3) * 16;
  u16 o[16];
#pragma unroll
  for (int i = 0; i < 16; ++i) o[i] = tile[wcol + i][wrow];
  u16* dst = Wt + (long long)(c0 + wrow) * E_DIM + r0 + wcol;
  *reinterpret_cast<u16x8*>(dst)     = *reinterpret_cast<u16x8*>(&o[0]);
  *reinterpret_cast<u16x8*>(dst + 8) = *reinterpret_cast<u16x8*>(&o[8]);
}

// ---------------- rope tables (double precision trig) ----------------
__global__ __launch_bounds__(256) void rope_tables_k(
    float* __restrict__ cost, float* __restrict__ sint) {
  int idx = blockIdx.x * 256 + threadIdx.x;
  int i = idx & 63, t = idx >> 6;
  double inv = pow(10000.0, -(double)i / 64.0);
  double ang = (double)t * inv;
  cost[idx] = (float)cos(ang);
  sint[idx] = (float)sin(ang);
}

// ---------------- fused rope + rmsnorm (in-place on bf16 Q and K) ----------
__global__ __launch_bounds__(256) void rope_rms_k(
    u16* __restrict__ Qb, u16* __restrict__ Kb, const float* __restrict__ cost,
    const float* __restrict__ sint) {
  int half = gridDim.x >> 1;
  int isK = blockIdx.x >= half;
  u16* qk = isK ? Kb : Qb;
  float outscale = isK ? 1.0f : 0.08838834764831845f;  // fold 1/sqrt(128) into Q
  int wave = threadIdx.x >> 6;
  int lane = threadIdx.x & 63;
  long long row = (long long)(blockIdx.x - (isK ? half : 0)) * 4 + wave;
  int th = (int)(row >> 4);
  int t = th & (T_SEQ - 1);
  u16* p = qk + row * HDIM;
  float x1 = b2f(p[lane]);
  float x2 = b2f(p[lane + 64]);
  float c = cost[t * 64 + lane];
  float s = sint[t * 64 + lane];
  float o1 = x1 * c - x2 * s;
  float o2 = x1 * s + x2 * c;
  float ss = o1 * o1 + o2 * o2;
#pragma unroll
  for (int m = 32; m >= 1; m >>= 1) ss += __shfl_xor(ss, m, 64);
  float r = rsqrtf(ss * (1.0f / 128.0f) + RMS_EPS) * outscale;
  p[lane] = f2b(o1 * r);
  p[lane + 64] = f2b(o2 * r);
}

// ---------------- V transpose: [B,T,H,D] -> per (b,h): [D][T] ----------------
__global__ __launch_bounds__(256) void transpose_v_k(
    const u16* __restrict__ V, u16* __restrict__ Vt) {
  __shared__ u16 tile[64][72];
  int t0 = blockIdx.x * 64, d0 = blockIdx.y * 64;
  int bh = blockIdx.z;
  int b = bh >> 4, h = bh & 15;
  int tid = threadIdx.x;
  int lrow = tid >> 3;
  int lcol = (tid & 7) * 8;
#pragma unroll
  for (int pass = 0; pass < 2; ++pass) {
    int row = lrow + pass * 32;
    const u16* src = V + ((((long long)b * T_SEQ + t0 + row) * NHEAD + h) << 7) + d0 + lcol;
    *reinterpret_cast<u16x8*>(&tile[row][lcol]) = *reinterpret_cast<const u16x8*>(src);
  }
  __syncthreads();
#pragma unroll
  for (int pass = 0; pass < 2; ++pass) {
    int drow = (tid >> 3) + pass * 32;
    int tcol = (tid & 7) * 8;
    u16x8 o;
#pragma unroll
    for (int i = 0; i < 8; ++i) o[i] = tile[tcol + i][drow];
    u16* dst = Vt + ((long long)bh * HDIM + d0 + drow) * T_SEQ + t0 + tcol;
    *reinterpret_cast<u16x8*>(dst) = o;
  }
}

// ---------------- bf16 MFMA GEMM: 256x256 tile, pipelined 8-phase ----------
// C[M,N] = A[M,K] * Bt[N,K]^T.  512 threads = 8 waves (2M x 4N), each wave
// owns 128x64 output (8x4 frags of 16x16, mfma_f32_16x16x32_bf16, BK=64).
// LDS: 2 x (A 256x64 + B 256x64) bf16 = 128 KiB, double buffered (1 WG/CU).
// Cross-phase pipelined ds_reads: phase p issues fragments for p+1; MFMA of
// p consumes fragments read in p-1 (compiler emits counted lgkmcnt -> LDS
// drain overlaps MFMA).  REGISTER BUDGET (the R3 lesson): 2 waves/SIMD caps
// VGPR at 256/wave; acc(128) + aX/aY(32) + bB(32) + addr ~= 222 fits; a
// second B set spilled to scratch and poisoned the vmcnt ledger.  bB is
// reloaded once per tile AFTER its last MFMA use (in-order issue makes the
// WAR safe); the reads drain across the p4 barrier, hidden by lgkmcnt(4).
// vmcnt(6)@p2 publishes B(t+1) (used p4), vmcnt(4)@p3 publishes A(t+1)
// (used p4); tail iteration tightens to 4/0.
__global__ __launch_bounds__(512, 2) void gemm_bt_k(
    const u16* __restrict__ A,
    const u16* __restrict__ Bt0, const u16* __restrict__ Bt1, const u16* __restrict__ Bt2,
    u16* __restrict__ C0, u16* __restrict__ C1, u16* __restrict__ C2,
    float* __restrict__ Cf, int M, int N, int K) {
  // ---- XCD-aware tile remap (bijective; gx=8, gy=32, gz in {1,3}) ----
  int lin = blockIdx.x + (blockIdx.y << 3) + (blockIdx.z << 8);
  int kx = lin & 7, ii = lin >> 3;
  int by = ((kx >> 1) << 3) + (ii & 7);   // m-tile: 8-chunk per XCD-pair class
  int bx, bz;
  if (gridDim.z == 3) {
    int u = (kx & 1) * 12 + (ii >> 3);    // 24 (n,z) tiles split in two 12-slices
    bx = u & 7; bz = u >> 3;
  } else {
    bx = ((kx & 1) << 2) + (ii >> 3);     // 8 n-tiles split in two 4-slices
    bz = 0;
  }
  const u16* Bt = bz == 0 ? Bt0 : (bz == 1 ? Bt1 : Bt2);
  u16* C = bz == 0 ? C0 : (bz == 1 ? C1 : C2);

  __shared__ u16 As[2][256 * 64];
  __shared__ u16 Bs[2][256 * 64];
  u16* A0 = As[0]; u16* A1 = As[1];
  u16* B0 = Bs[0]; u16* B1 = Bs[1];
  const int tid = threadIdx.x;
  const int lane = tid & 63, wave = tid >> 6;
  const int wm = wave >> 2, wn = wave & 3;   // 2 x 4 wave grid
  const int m0 = by * 256, n0 = bx * 256;
  const int lr = lane & 15, lq = lane >> 4, l7 = lane & 7;
  const int NT = K >> 6;

  // Staging halves: A half h = rows with bit6==h; B half h = rows bit5==h.
  int rowA[2][2], rowB[2][2];
  const u16* gA[2][2];
  const u16* gB[2][2];
#pragma unroll
  for (int l = 0; l < 2; ++l) {
    int rihb = l * 64 + wave * 8;
#pragma unroll
    for (int h = 0; h < 2; ++h) {
      int ra = ((rihb >> 6) << 7) + h * 64 + (rihb & 63);
      int rb = ((rihb >> 5) << 6) + h * 32 + (rihb & 31);
      rowA[h][l] = ra;
      rowB[h][l] = rb;
      int rA = ra + (lane >> 3);
      int rB = rb + (lane >> 3);
      // inverse-swizzled global source: LDS[r][c] <- G[r][c ^ (r&7)]
      gA[h][l] = A + (long long)(m0 + rA) * K + ((l7 ^ (rA & 7)) * 8);
      gB[h][l] = Bt + (long long)(n0 + rB) * K + ((l7 ^ (rB & 7)) * 8);
    }
  }

  f32x4 acc[8][4] = {};
  bf16x8 aX[2][2], aY[2][2], bB[4][2];

#define GLDS(gp, lp) \
  __builtin_amdgcn_global_load_lds((g_u32*)(gp), (l_u32*)(lp), 16, 0, 0)
#define STG_A(bufp, h, off) do {                                              \
    GLDS(gA[h][0] + (off), (bufp) + rowA[h][0] * 64);                         \
    GLDS(gA[h][1] + (off), (bufp) + rowA[h][1] * 64); } while (0)
#define STG_B(bufp, h, off) do {                                              \
    GLDS(gB[h][0] + (off), (bufp) + rowB[h][0] * 64);                         \
    GLDS(gB[h][1] + (off), (bufp) + rowB[h][1] * 64); } while (0)
#define LDSA(dst, buf, mtb)                                                   \
  _Pragma("unroll") for (int mi = 0; mi < 2; ++mi)                            \
  _Pragma("unroll") for (int ks = 0; ks < 2; ++ks)                            \
    dst[mi][ks] = *reinterpret_cast<const bf16x8*>(                           \
        (buf) + (wm * 128 + ((mtb) + mi) * 16 + lr) * 64 +                    \
        ((((ks) << 2) + lq) ^ l7) * 8);
#define LDSB(dst, buf)                                                        \
  _Pragma("unroll") for (int ni = 0; ni < 4; ++ni)                            \
  _Pragma("unroll") for (int ks = 0; ks < 2; ++ks)                            \
    dst[ni][ks] = *reinterpret_cast<const bf16x8*>(                           \
        (buf) + (wn * 64 + (ni) * 16 + lr) * 64 +                             \
        ((((ks) << 2) + lq) ^ l7) * 8);
#define MFMA2(ph, a)                                                          \
  _Pragma("unroll") for (int mi = 0; mi < 2; ++mi)                            \
  _Pragma("unroll") for (int ni = 0; ni < 4; ++ni)                            \
  _Pragma("unroll") for (int ks = 0; ks < 2; ++ks)                            \
    acc[(ph) * 2 + mi][ni] = __builtin_amdgcn_mfma_f32_16x16x32_bf16(         \
        a[mi][ks], bB[ni][ks], acc[(ph) * 2 + mi][ni], 0, 0, 0);
#define SB __builtin_amdgcn_sched_barrier(0)
#define BAR __builtin_amdgcn_s_barrier()
#define VMC(n) asm volatile("s_waitcnt vmcnt(" #n ")" ::: "memory")
#define PH_MID SB; BAR; SB; __builtin_amdgcn_s_setprio(1)
#define PH_END __builtin_amdgcn_s_setprio(0); SB; BAR; SB

  // prologue: tile0 (8 loads) + tile1 {B(1,h0),B(1,h1),A(1,h0)} (6 loads);
  // vmcnt(6) completes tile0, keeps 3 halves in flight; preload fragments.
  GLDS(gB[0][0], B0 + rowB[0][0] * 64); GLDS(gB[0][1], B0 + rowB[0][1] * 64);
  GLDS(gB[1][0], B0 + rowB[1][0] * 64); GLDS(gB[1][1], B0 + rowB[1][1] * 64);
  GLDS(gA[0][0], A0 + rowA[0][0] * 64); GLDS(gA[0][1], A0 + rowA[0][1] * 64);
  GLDS(gA[1][0], A0 + rowA[1][0] * 64); GLDS(gA[1][1], A0 + rowA[1][1] * 64);
  GLDS(gB[0][0] + 64, B1 + rowB[0][0] * 64); GLDS(gB[0][1] + 64, B1 + rowB[0][1] * 64);
  GLDS(gB[1][0] + 64, B1 + rowB[1][0] * 64); GLDS(gB[1][1] + 64, B1 + rowB[1][1] * 64);
  GLDS(gA[0][0] + 64, A1 + rowA[0][0] * 64); GLDS(gA[0][1] + 64, A1 + rowA[0][1] * 64);
  VMC(6);
  BAR; SB;
  LDSB(bB, B0);
  LDSA(aX, A0, 0);
  SB;

#pragma unroll 1
  for (int t = 0; t < NT; t += 2) {
    const bool nl = (t + 2 < NT);       // not last iteration
    // ===== tile t (A regs from A0, bB holds B(t)) =====
    // p1: prefetch aY(mt2,3); stage A(t+1,h1)->A1
    LDSA(aY, A0, 2);
    STG_A(A1, 1, 64);
    PH_MID; MFMA2(0, aX); PH_END;
    // p2: prefetch aX(mt4,5); stage B(t+2,h0)->B0; publish B(t+1)
    LDSA(aX, A0, 4);
    if (nl) { STG_B(B0, 0, 128); VMC(6); } else { VMC(4); }
    PH_MID; MFMA2(1, aY); PH_END;
    // p3: prefetch aY(mt6,7); stage B(t+2,h1)->B0; publish A(t+1)
    LDSA(aY, A0, 6);
    if (nl) { STG_B(B0, 1, 128); VMC(4); } else { VMC(0); }
    PH_MID; MFMA2(2, aX); PH_END;
    // p4: prefetch aX(t+1,mt0,1); stage A(t+2,h0)->A0;
    //     reload bB <- B(t+1) AFTER last use (in-order issue: WAR safe)
    LDSA(aX, A1, 0);
    if (nl) STG_A(A0, 0, 128);
    PH_MID; MFMA2(3, aY);
    LDSB(bB, B1);
    PH_END;
    // ===== tile t+1 (A regs from A1, bB holds B(t+1)) =====
    // p1': prefetch aY; stage A(t+2,h1)->A0
    LDSA(aY, A1, 2);
    if (nl) STG_A(A0, 1, 128);
    PH_MID; MFMA2(0, aX); PH_END;
    // p2': prefetch aX; stage B(t+3,h0)->B1; publish B(t+2)
    LDSA(aX, A1, 4);
    if (nl) { STG_B(B1, 0, 192); VMC(6); }
    PH_MID; MFMA2(1, aY); PH_END;
    // p3': prefetch aY; stage B(t+3,h1)->B1; publish A(t+2)
    LDSA(aY, A1, 6);
    if (nl) { STG_B(B1, 1, 192); VMC(4); }
    PH_MID; MFMA2(2, aX); PH_END;
    // p4': prefetch aX(t+2,mt0,1); stage A(t+3,h0)->A1; reload bB <- B(t+2)
    LDSA(aX, A0, 0);
    if (nl) STG_A(A1, 0, 192);
    PH_MID; MFMA2(3, aY);
    LDSB(bB, B0);
    PH_END;
    // advance 2 K-tiles
#pragma unroll
    for (int l = 0; l < 2; ++l)
#pragma unroll
      for (int h = 0; h < 2; ++h) { gA[h][l] += 128; gB[h][l] += 128; }
  }
#undef LDSA
#undef LDSB
#undef MFMA2
#undef STG_A
#undef STG_B
#undef GLDS
#undef PH_MID
#undef PH_END

  // epilogue: C col = lane&15, row = (lane>>4)*4 + reg   (16x16 C/D layout)
#pragma unroll
  for (int mt = 0; mt < 8; ++mt)
#pragma unroll
    for (int nt = 0; nt < 4; ++nt) {
      long long col = n0 + wn * 64 + nt * 16 + lr;
#pragma unroll
      for (int r = 0; r < 4; ++r) {
        long long row = m0 + wm * 128 + mt * 16 + lq * 4 + r;
        float v = acc[mt][nt][r];
        if (Cf) Cf[row * N + col] = v;
        else C[row * N + col] = f2b(v);
      }
    }
}

// ---------------- causal flash attention v3 (XCD-remapped grid) ----------
__global__ __launch_bounds__(256, 3) void attn_k(
    const u16* __restrict__ Q, const u16* __restrict__ K,
    const u16* __restrict__ Vt, u16* __restrict__ Y) {
  __shared__ u16 Ks[64 * 128];        // row=key, 16 chunks/row, slot=(g+key)&15
  __shared__ u16 Vs[128 * 64];        // row=d, 8 chunks/row, slot=(g+d)&7
  __shared__ u16 Ps[4][32 * 72];      // per-wave P [q][key], pad 64->72
  __shared__ float Al[4][32];         // per-wave alpha / l broadcast
  // XCD remap (hw xcd = lin%8; gx = NQT/2 = 8): XCD k owns bh in [8k, 8k+8)
  int lin = blockIdx.x + (blockIdx.y << 3);
  int pair = (lin >> 6);              // 0..NQT/2-1
  int bh = ((lin & 7) << 3) + ((lin >> 3) & 7);
  int b = bh >> 4, h = bh & 15;
  int tid = threadIdx.x, lane = tid & 63, wave = tid >> 6;
  int lr = lane & 15, lq = lane >> 4;

  const u16* kp[4];
  const u16* vp[4];
#pragma unroll
  for (int p = 0; p < 4; ++p) {
    int c = p * 256 + wave * 64 + lane;
    int key = c >> 4, sk = c & 15, gk = (sk - key) & 15;
    kp[p] = K + (((long long)b * T_SEQ + key) * NHEAD + h) * HDIM + gk * 8;
    int d = c >> 3, sv = c & 7, gv = (sv - d) & 7;
    vp[p] = Vt + ((long long)bh * HDIM + d) * T_SEQ + gv * 8;
  }

#pragma unroll 1
  for (int phase = 0; phase < 2; ++phase) {
    int qt = phase == 0 ? (NQT - 1 - pair) : pair;
    int qbase = qt * 128 + wave * 32;

    bf16x8 aq[2][4];
#pragma unroll
    for (int n2 = 0; n2 < 2; ++n2) {
      const u16* qp = Q + (((long long)b * T_SEQ + qbase + n2 * 16 + lr) * NHEAD + h) * HDIM;
#pragma unroll
      for (int kt = 0; kt < 4; ++kt)
        aq[n2][kt] = *reinterpret_cast<const bf16x8*>(qp + kt * 32 + lq * 8);
    }

    float m_s[2], l_s[2];
#pragma unroll
    for (int n2 = 0; n2 < 2; ++n2) { m_s[n2] = -INFINITY; l_s[n2] = 0.f; }
    f32x4 o[2][8] = {};

    int niter = 2 * qt + 2;
    for (int j = 0; j < niter; ++j) {
      __syncthreads();
#pragma unroll
      for (int p = 0; p < 4; ++p) {
        __builtin_amdgcn_global_load_lds(
            (g_u32*)(kp[p] + (long long)j * 64 * NHEAD * HDIM),
            (l_u32*)(Ks + p * 2048 + wave * 512), 16, 0, 0);
        __builtin_amdgcn_global_load_lds(
            (g_u32*)(vp[p] + j * 64),
            (l_u32*)(Vs + p * 2048 + wave * 512), 16, 0, 0);
      }
      __syncthreads();

      f32x4 s[4][2];
#pragma unroll
      for (int mt = 0; mt < 4; ++mt) {
        int key = mt * 16 + lr;
        bf16x8 ak[4];
#pragma unroll
        for (int kt = 0; kt < 4; ++kt) {
          int slot = (kt * 4 + lq + key) & 15;
          ak[kt] = *reinterpret_cast<const bf16x8*>(&Ks[key * 128 + slot * 8]);
        }
#pragma unroll
        for (int n2 = 0; n2 < 2; ++n2) {
          f32x4 acc = {};
#pragma unroll
          for (int kt = 0; kt < 4; ++kt)
            acc = __builtin_amdgcn_mfma_f32_16x16x32_bf16(ak[kt], aq[n2][kt], acc, 0, 0, 0);
          s[mt][n2] = acc;
        }
      }

      if (j >= 2 * qt) {
#pragma unroll
        for (int mt = 0; mt < 4; ++mt)
#pragma unroll
          for (int n2 = 0; n2 < 2; ++n2) {
            int q = qbase + n2 * 16 + lr;
#pragma unroll
            for (int r = 0; r < 4; ++r) {
              int key = j * 64 + mt * 16 + lq * 4 + r;
              if (key > q) s[mt][n2][r] = -INFINITY;
            }
          }
      }

      float alpha[2];
#pragma unroll
      for (int n2 = 0; n2 < 2; ++n2) {
        float mx = s[0][n2][0];
#pragma unroll
        for (int mt = 0; mt < 4; ++mt)
#pragma unroll
          for (int r = 0; r < 4; ++r) mx = fmaxf(mx, s[mt][n2][r]);
        mx = fmaxf(mx, __shfl_xor(mx, 16, 64));
        mx = fmaxf(mx, __shfl_xor(mx, 32, 64));
        float mn = fmaxf(m_s[n2], mx);
        alpha[n2] = __expf(m_s[n2] - mn);
        m_s[n2] = mn;
        float sum = 0.f;
        int q = n2 * 16 + lr;
#pragma unroll
        for (int mt = 0; mt < 4; ++mt) {
          ushort4 pk;
          float p0 = __expf(s[mt][n2][0] - mn);
          float p1 = __expf(s[mt][n2][1] - mn);
          float p2 = __expf(s[mt][n2][2] - mn);
          float p3 = __expf(s[mt][n2][3] - mn);
          sum += (p0 + p1) + (p2 + p3);
          pk.x = f2b(p0); pk.y = f2b(p1); pk.z = f2b(p2); pk.w = f2b(p3);
          *reinterpret_cast<ushort4*>(&Ps[wave][q * 72 + mt * 16 + lq * 4]) = pk;
        }
        sum += __shfl_xor(sum, 16, 64);
        sum += __shfl_xor(sum, 32, 64);
        l_s[n2] = l_s[n2] * alpha[n2] + sum;
      }

      if (lq == 0) {
        Al[wave][lr] = alpha[0];
        Al[wave][16 + lr] = alpha[1];
      }
#pragma unroll
      for (int q2 = 0; q2 < 2; ++q2) {
        f32x4 av = *reinterpret_cast<const f32x4*>(&Al[wave][q2 * 16 + lq * 4]);
#pragma unroll
        for (int r = 0; r < 4; ++r)
#pragma unroll
          for (int dt = 0; dt < 8; ++dt) o[q2][dt][r] *= av[r];
      }

#pragma unroll
      for (int kh = 0; kh < 2; ++kh) {
        bf16x8 ap[2];
#pragma unroll
        for (int q2 = 0; q2 < 2; ++q2)
          ap[q2] = *reinterpret_cast<const bf16x8*>(
              &Ps[wave][(q2 * 16 + lr) * 72 + kh * 32 + lq * 8]);
#pragma unroll
        for (int dt = 0; dt < 8; ++dt) {
          int d = dt * 16 + lr;
          int slot = (kh * 4 + lq + d) & 7;
          bf16x8 bv = *reinterpret_cast<const bf16x8*>(&Vs[d * 64 + slot * 8]);
#pragma unroll
          for (int q2 = 0; q2 < 2; ++q2)
            o[q2][dt] = __builtin_amdgcn_mfma_f32_16x16x32_bf16(ap[q2], bv, o[q2][dt], 0, 0, 0);
        }
      }
    }

    if (lq == 0) {
      Al[wave][lr] = l_s[0];
      Al[wave][16 + lr] = l_s[1];
    }
#pragma unroll
    for (int q2 = 0; q2 < 2; ++q2) {
      f32x4 lv = *reinterpret_cast<const f32x4*>(&Al[wave][q2 * 16 + lq * 4]);
#pragma unroll
      for (int r = 0; r < 4; ++r) {
        float inv = 1.0f / lv[r];
        int q = qbase + q2 * 16 + lq * 4 + r;
        u16* yp = Y + (((long long)b * T_SEQ + q) * NHEAD + h) * HDIM;
#pragma unroll
        for (int dt = 0; dt < 8; ++dt)
          yp[dt * 16 + lr] = f2b(o[q2][dt][r] * inv);
      }
    }
  }
}

extern "C" void kernel_launch(void* const* d_in, const int* in_sizes, int n_in,
                              void* d_out, int out_size, void* d_ws, size_t ws_size,
                              hipStream_t stream) {
  (void)in_sizes; (void)n_in; (void)out_size; (void)ws_size;
  const float* x  = (const float*)d_in[0];
  const float* wq = (const float*)d_in[1];
  const float* wk = (const float*)d_in[2];
  const float* wv = (const float*)d_in[3];
  const float* wo = (const float*)d_in[4];
  float* out = (float*)d_out;

  char* ws = (char*)d_ws;
  size_t off = 0;
  auto alloc = [&](size_t bytes) {
    char* p = ws + off;
    off += (bytes + 255) & ~(size_t)255;
    return p;
  };
  const size_t NTOK = (size_t)BATCH * T_SEQ;
  const size_t XE = NTOK * E_DIM;
  const size_t WE = (size_t)E_DIM * E_DIM;

  u16* xb  = (u16*)alloc(XE * 2);
  u16* wqt = (u16*)alloc(WE * 2);
  u16* wkt = (u16*)alloc(WE * 2);
  u16* wvt = (u16*)alloc(WE * 2);
  u16* wot = (u16*)alloc(WE * 2);
  u16* Qb  = (u16*)alloc(XE * 2);
  u16* Kb  = (u16*)alloc(XE * 2);
  u16* Vb  = (u16*)alloc(XE * 2);
  u16* Vt  = (u16*)alloc(XE * 2);
  u16* Yb  = (u16*)alloc(XE * 2);
  float* cost = (float*)alloc((size_t)T_SEQ * 64 * 4);
  float* sint = (float*)alloc((size_t)T_SEQ * 64 * 4);

  convert_f32_bf16<<<XE / 1024, 256, 0, stream>>>(x, xb, (int)XE);
  dim3 gw(E_DIM / 64, E_DIM / 64);
  convt_w_k<<<gw, 256, 0, stream>>>(wq, wqt);
  convt_w_k<<<gw, 256, 0, stream>>>(wk, wkt);
  convt_w_k<<<gw, 256, 0, stream>>>(wv, wvt);
  convt_w_k<<<gw, 256, 0, stream>>>(wo, wot);
  rope_tables_k<<<(T_SEQ * 64) / 256, 256, 0, stream>>>(cost, sint);

  dim3 gq(E_DIM / 256, NTOK / 256, 3);
  gemm_bt_k<<<gq, 512, 0, stream>>>(xb, wqt, wkt, wvt, Qb, Kb, Vb, nullptr,
                                    (int)NTOK, E_DIM, E_DIM);

  rope_rms_k<<<(unsigned)(NTOK * NHEAD / 4) * 2, 256, 0, stream>>>(Qb, Kb, cost, sint);

  dim3 gt(T_SEQ / 64, HDIM / 64, BATCH * NHEAD);
  transpose_v_k<<<gt, 256, 0, stream>>>(Vb, Vt);

  dim3 ga(NQT / 2, BATCH * NHEAD);
  attn_k<<<ga, 256, 0, stream>>>(Qb, Kb, Vt, Yb);

  dim3 go(E_DIM / 256, NTOK / 256, 1);
  gemm_bt_k<<<go, 512, 0, stream>>>(Yb, wot, wot, wot, nullptr, nullptr, nullptr, out,
                                    (int)NTOK, E_DIM, E_DIM);
}

// Round 5
// 618.902 us; speedup vs baseline: 1.2710x; 1.0155x over previous
//
#include <hip/hip_runtime.h>
#include <math.h>

#define T_SEQ 2048
#define BATCH 4
#define E_DIM 2048
#define NHEAD 16
#define HDIM 128
#define RMS_EPS 1.1920929e-07f
#define NQT (T_SEQ / 128)          // 16 q-tiles of 128

typedef unsigned short u16;
typedef __attribute__((ext_vector_type(8))) unsigned short u16x8;
typedef __attribute__((ext_vector_type(8))) short bf16x8;
typedef __attribute__((ext_vector_type(4))) float f32x4;

typedef const __attribute__((address_space(1))) unsigned int g_u32;
typedef __attribute__((address_space(3))) unsigned int l_u32;

static __device__ __forceinline__ u16 f2b(float f) {
  unsigned int u = __builtin_bit_cast(unsigned int, f);
  u += 0x7fffu + ((u >> 16) & 1u);
  return (u16)(u >> 16);
}
static __device__ __forceinline__ float b2f(u16 v) {
  return __builtin_bit_cast(float, ((unsigned int)v) << 16);
}

// ---------------- fp32 -> bf16 convert (x only) ----------------
__global__ __launch_bounds__(256) void convert_f32_bf16(
    const float* __restrict__ src, u16* __restrict__ dst, int n) {
  int i = (blockIdx.x * 256 + threadIdx.x) * 4;
  if (i >= n) return;
  float4 v = *reinterpret_cast<const float4*>(src + i);
  ushort4 o;
  o.x = f2b(v.x); o.y = f2b(v.y); o.z = f2b(v.z); o.w = f2b(v.w);
  *reinterpret_cast<ushort4*>(dst + i) = o;
}

// ---------------- fused fp32->bf16 convert + transpose: Wt[n][k]=W[k][n] ----
__global__ __launch_bounds__(256) void convt_w_k(
    const float* __restrict__ W, u16* __restrict__ Wt) {
  __shared__ u16 tile[64][72];
  int c0 = blockIdx.x * 64;
  int r0 = blockIdx.y * 64;
  int tid = threadIdx.x;
  int lrow = tid >> 2;
  int lcol = (tid & 3) * 16;
#pragma unroll
  for (int i = 0; i < 4; ++i) {
    float4 v = *reinterpret_cast<const float4*>(
        W + (long long)(r0 + lrow) * E_DIM + c0 + lcol + i * 4);
    tile[lrow][lcol + i * 4 + 0] = f2b(v.x);
    tile[lrow][lcol + i * 4 + 1] = f2b(v.y);
    tile[lrow][lcol + i * 4 + 2] = f2b(v.z);
    tile[lrow][lcol + i * 4 + 3] = f2b(v.w);
  }
  __syncthreads();
  int wrow = tid >> 2;
  int wcol = (tid & 3) * 16;
  u16 o[16];
#pragma unroll
  for (int i = 0; i < 16; ++i) o[i] = tile[wcol + i][wrow];
  u16* dst = Wt + (long long)(c0 + wrow) * E_DIM + r0 + wcol;
  *reinterpret_cast<u16x8*>(dst)     = *reinterpret_cast<u16x8*>(&o[0]);
  *reinterpret_cast<u16x8*>(dst + 8) = *reinterpret_cast<u16x8*>(&o[8]);
}

// ---------------- rope tables (double precision trig) ----------------
__global__ __launch_bounds__(256) void rope_tables_k(
    float* __restrict__ cost, float* __restrict__ sint) {
  int idx = blockIdx.x * 256 + threadIdx.x;
  int i = idx & 63, t = idx >> 6;
  double inv = pow(10000.0, -(double)i / 64.0);
  double ang = (double)t * inv;
  cost[idx] = (float)cos(ang);
  sint[idx] = (float)sin(ang);
}

// ---------------- fused rope + rmsnorm (in-place on bf16 Q and K) ----------
__global__ __launch_bounds__(256) void rope_rms_k(
    u16* __restrict__ Qb, u16* __restrict__ Kb, const float* __restrict__ cost,
    const float* __restrict__ sint) {
  int half = gridDim.x >> 1;
  int isK = blockIdx.x >= half;
  u16* qk = isK ? Kb : Qb;
  float outscale = isK ? 1.0f : 0.08838834764831845f;  // fold 1/sqrt(128) into Q
  int wave = threadIdx.x >> 6;
  int lane = threadIdx.x & 63;
  long long row = (long long)(blockIdx.x - (isK ? half : 0)) * 4 + wave;
  int th = (int)(row >> 4);
  int t = th & (T_SEQ - 1);
  u16* p = qk + row * HDIM;
  float x1 = b2f(p[lane]);
  float x2 = b2f(p[lane + 64]);
  float c = cost[t * 64 + lane];
  float s = sint[t * 64 + lane];
  float o1 = x1 * c - x2 * s;
  float o2 = x1 * s + x2 * c;
  float ss = o1 * o1 + o2 * o2;
#pragma unroll
  for (int m = 32; m >= 1; m >>= 1) ss += __shfl_xor(ss, m, 64);
  float r = rsqrtf(ss * (1.0f / 128.0f) + RMS_EPS) * outscale;
  p[lane] = f2b(o1 * r);
  p[lane + 64] = f2b(o2 * r);
}

// ---------------- V transpose: [B,T,H,D] -> per (b,h): [D][T] ----------------
__global__ __launch_bounds__(256) void transpose_v_k(
    const u16* __restrict__ V, u16* __restrict__ Vt) {
  __shared__ u16 tile[64][72];
  int t0 = blockIdx.x * 64, d0 = blockIdx.y * 64;
  int bh = blockIdx.z;
  int b = bh >> 4, h = bh & 15;
  int tid = threadIdx.x;
  int lrow = tid >> 3;
  int lcol = (tid & 7) * 8;
#pragma unroll
  for (int pass = 0; pass < 2; ++pass) {
    int row = lrow + pass * 32;
    const u16* src = V + ((((long long)b * T_SEQ + t0 + row) * NHEAD + h) << 7) + d0 + lcol;
    *reinterpret_cast<u16x8*>(&tile[row][lcol]) = *reinterpret_cast<const u16x8*>(src);
  }
  __syncthreads();
#pragma unroll
  for (int pass = 0; pass < 2; ++pass) {
    int drow = (tid >> 3) + pass * 32;
    int tcol = (tid & 7) * 8;
    u16x8 o;
#pragma unroll
    for (int i = 0; i < 8; ++i) o[i] = tile[tcol + i][drow];
    u16* dst = Vt + ((long long)bh * HDIM + d0 + drow) * T_SEQ + t0 + tcol;
    *reinterpret_cast<u16x8*>(dst) = o;
  }
}

// ---------------- bf16 MFMA GEMM: 256x256 tile, pipelined 4-phase ----------
// C[M,N] = A[M,K] * Bt[N,K]^T.  512 threads = 8 waves (2M x 4N), each wave
// owns 128x64 output (8x4 frags of 16x16, mfma_f32_16x16x32_bf16, BK=64).
// LDS: 2 x (A 256x64 + B 256x64) bf16 = 128 KiB, double buffered (1 WG/CU).
// R5 change: ONE barrier per phase (the MID barrier) instead of two.  The
// MID barrier carries the publish protocol (every vmcnt(N) executes
// immediately before it, so VMC-by-all-waves + barrier makes staged LDS
// globally visible).  All stage-writes target regions whose readers are
// >=2 MID-barriers away; skew <=1 phase + in-order LDS queue + >=200cyc
// write-arrival keeps it race-free.  Registers/ledger identical to R4:
// acc(128 AGPR) + aX/aY(16+16) + bB(32) + addr ~= 252/wave (2 waves/SIMD
// cap is 256 -- do NOT add fragment sets, R3 spilled at +32).
// VMC(6)@p2 publishes B(t+1) (bB reload @p4-end); VMC(4)@p3 publishes
// A(t+1) (aX read @p4-start); tail tightens to 4/0.
__global__ __launch_bounds__(512, 2) void gemm_bt_k(
    const u16* __restrict__ A,
    const u16* __restrict__ Bt0, const u16* __restrict__ Bt1, const u16* __restrict__ Bt2,
    u16* __restrict__ C0, u16* __restrict__ C1, u16* __restrict__ C2,
    float* __restrict__ Cf, int M, int N, int K) {
  // ---- XCD-aware tile remap (bijective; gx=8, gy=32, gz in {1,3}) ----
  int lin = blockIdx.x + (blockIdx.y << 3) + (blockIdx.z << 8);
  int kx = lin & 7, ii = lin >> 3;
  int by = ((kx >> 1) << 3) + (ii & 7);   // m-tile: 8-chunk per XCD-pair class
  int bx, bz;
  if (gridDim.z == 3) {
    int u = (kx & 1) * 12 + (ii >> 3);    // 24 (n,z) tiles split in two 12-slices
    bx = u & 7; bz = u >> 3;
  } else {
    bx = ((kx & 1) << 2) + (ii >> 3);     // 8 n-tiles split in two 4-slices
    bz = 0;
  }
  const u16* Bt = bz == 0 ? Bt0 : (bz == 1 ? Bt1 : Bt2);
  u16* C = bz == 0 ? C0 : (bz == 1 ? C1 : C2);

  __shared__ u16 As[2][256 * 64];
  __shared__ u16 Bs[2][256 * 64];
  u16* A0 = As[0]; u16* A1 = As[1];
  u16* B0 = Bs[0]; u16* B1 = Bs[1];
  const int tid = threadIdx.x;
  const int lane = tid & 63, wave = tid >> 6;
  const int wm = wave >> 2, wn = wave & 3;   // 2 x 4 wave grid
  const int m0 = by * 256, n0 = bx * 256;
  const int lr = lane & 15, lq = lane >> 4, l7 = lane & 7;
  const int NT = K >> 6;

  // Staging halves: A half h = rows with bit6==h; B half h = rows bit5==h.
  int rowA[2][2], rowB[2][2];
  const u16* gA[2][2];
  const u16* gB[2][2];
#pragma unroll
  for (int l = 0; l < 2; ++l) {
    int rihb = l * 64 + wave * 8;
#pragma unroll
    for (int h = 0; h < 2; ++h) {
      int ra = ((rihb >> 6) << 7) + h * 64 + (rihb & 63);
      int rb = ((rihb >> 5) << 6) + h * 32 + (rihb & 31);
      rowA[h][l] = ra;
      rowB[h][l] = rb;
      int rA = ra + (lane >> 3);
      int rB = rb + (lane >> 3);
      // inverse-swizzled global source: LDS[r][c] <- G[r][c ^ (r&7)]
      gA[h][l] = A + (long long)(m0 + rA) * K + ((l7 ^ (rA & 7)) * 8);
      gB[h][l] = Bt + (long long)(n0 + rB) * K + ((l7 ^ (rB & 7)) * 8);
    }
  }

  f32x4 acc[8][4] = {};
  bf16x8 aX[2][2], aY[2][2], bB[4][2];

#define GLDS(gp, lp) \
  __builtin_amdgcn_global_load_lds((g_u32*)(gp), (l_u32*)(lp), 16, 0, 0)
#define STG_A(bufp, h, off) do {                                              \
    GLDS(gA[h][0] + (off), (bufp) + rowA[h][0] * 64);                         \
    GLDS(gA[h][1] + (off), (bufp) + rowA[h][1] * 64); } while (0)
#define STG_B(bufp, h, off) do {                                              \
    GLDS(gB[h][0] + (off), (bufp) + rowB[h][0] * 64);                         \
    GLDS(gB[h][1] + (off), (bufp) + rowB[h][1] * 64); } while (0)
#define LDSA(dst, buf, mtb)                                                   \
  _Pragma("unroll") for (int mi = 0; mi < 2; ++mi)                            \
  _Pragma("unroll") for (int ks = 0; ks < 2; ++ks)                            \
    dst[mi][ks] = *reinterpret_cast<const bf16x8*>(                           \
        (buf) + (wm * 128 + ((mtb) + mi) * 16 + lr) * 64 +                    \
        ((((ks) << 2) + lq) ^ l7) * 8);
#define LDSB(dst, buf)                                                        \
  _Pragma("unroll") for (int ni = 0; ni < 4; ++ni)                            \
  _Pragma("unroll") for (int ks = 0; ks < 2; ++ks)                            \
    dst[ni][ks] = *reinterpret_cast<const bf16x8*>(                           \
        (buf) + (wn * 64 + (ni) * 16 + lr) * 64 +                             \
        ((((ks) << 2) + lq) ^ l7) * 8);
#define MFMA2(ph, a)                                                          \
  _Pragma("unroll") for (int mi = 0; mi < 2; ++mi)                            \
  _Pragma("unroll") for (int ni = 0; ni < 4; ++ni)                            \
  _Pragma("unroll") for (int ks = 0; ks < 2; ++ks)                            \
    acc[(ph) * 2 + mi][ni] = __builtin_amdgcn_mfma_f32_16x16x32_bf16(         \
        a[mi][ks], bB[ni][ks], acc[(ph) * 2 + mi][ni], 0, 0, 0);
#define SB __builtin_amdgcn_sched_barrier(0)
#define BAR __builtin_amdgcn_s_barrier()
#define VMC(n) asm volatile("s_waitcnt vmcnt(" #n ")" ::: "memory")
#define PH_MID SB; BAR; SB; __builtin_amdgcn_s_setprio(1)
#define PH_END __builtin_amdgcn_s_setprio(0); SB     /* R5: no barrier here */

  // prologue: tile0 (8 loads) + tile1 {B(1,h0),B(1,h1),A(1,h0)} (6 loads);
  // vmcnt(6) completes tile0, keeps 3 halves in flight; preload fragments.
  GLDS(gB[0][0], B0 + rowB[0][0] * 64); GLDS(gB[0][1], B0 + rowB[0][1] * 64);
  GLDS(gB[1][0], B0 + rowB[1][0] * 64); GLDS(gB[1][1], B0 + rowB[1][1] * 64);
  GLDS(gA[0][0], A0 + rowA[0][0] * 64); GLDS(gA[0][1], A0 + rowA[0][1] * 64);
  GLDS(gA[1][0], A0 + rowA[1][0] * 64); GLDS(gA[1][1], A0 + rowA[1][1] * 64);
  GLDS(gB[0][0] + 64, B1 + rowB[0][0] * 64); GLDS(gB[0][1] + 64, B1 + rowB[0][1] * 64);
  GLDS(gB[1][0] + 64, B1 + rowB[1][0] * 64); GLDS(gB[1][1] + 64, B1 + rowB[1][1] * 64);
  GLDS(gA[0][0] + 64, A1 + rowA[0][0] * 64); GLDS(gA[0][1] + 64, A1 + rowA[0][1] * 64);
  VMC(6);
  BAR; SB;
  LDSB(bB, B0);
  LDSA(aX, A0, 0);
  SB;

#pragma unroll 1
  for (int t = 0; t < NT; t += 2) {
    const bool nl = (t + 2 < NT);       // not last iteration
    // ===== tile t (A regs from A0, bB holds B(t)) =====
    // p1: prefetch aY(mt2,3); stage A(t+1,h1)->A1
    LDSA(aY, A0, 2);
    STG_A(A1, 1, 64);
    PH_MID; MFMA2(0, aX); PH_END;
    // p2: prefetch aX(mt4,5); stage B(t+2,h0)->B0; publish B(t+1)
    LDSA(aX, A0, 4);
    if (nl) { STG_B(B0, 0, 128); VMC(6); } else { VMC(4); }
    PH_MID; MFMA2(1, aY); PH_END;
    // p3: prefetch aY(mt6,7); stage B(t+2,h1)->B0; publish A(t+1)
    LDSA(aY, A0, 6);
    if (nl) { STG_B(B0, 1, 128); VMC(4); } else { VMC(0); }
    PH_MID; MFMA2(2, aX); PH_END;
    // p4: prefetch aX(t+1,mt0,1); stage A(t+2,h0)->A0;
    //     reload bB <- B(t+1) AFTER last use (in-order issue: WAR safe)
    LDSA(aX, A1, 0);
    if (nl) STG_A(A0, 0, 128);
    PH_MID; MFMA2(3, aY);
    LDSB(bB, B1);
    PH_END;
    // ===== tile t+1 (A regs from A1, bB holds B(t+1)) =====
    // p1': prefetch aY; stage A(t+2,h1)->A0
    LDSA(aY, A1, 2);
    if (nl) STG_A(A0, 1, 128);
    PH_MID; MFMA2(0, aX); PH_END;
    // p2': prefetch aX; stage B(t+3,h0)->B1; publish B(t+2)
    LDSA(aX, A1, 4);
    if (nl) { STG_B(B1, 0, 192); VMC(6); }
    PH_MID; MFMA2(1, aY); PH_END;
    // p3': prefetch aY; stage B(t+3,h1)->B1; publish A(t+2)
    LDSA(aY, A1, 6);
    if (nl) { STG_B(B1, 1, 192); VMC(4); }
    PH_MID; MFMA2(2, aX); PH_END;
    // p4': prefetch aX(t+2,mt0,1); stage A(t+3,h0)->A1; reload bB <- B(t+2)
    LDSA(aX, A0, 0);
    if (nl) STG_A(A1, 0, 192);
    PH_MID; MFMA2(3, aY);
    LDSB(bB, B0);
    PH_END;
    // advance 2 K-tiles
#pragma unroll
    for (int l = 0; l < 2; ++l)
#pragma unroll
      for (int h = 0; h < 2; ++h) { gA[h][l] += 128; gB[h][l] += 128; }
  }
#undef LDSA
#undef LDSB
#undef MFMA2
#undef STG_A
#undef STG_B
#undef GLDS
#undef PH_MID
#undef PH_END

  // epilogue: C col = lane&15, row = (lane>>4)*4 + reg   (16x16 C/D layout)
#pragma unroll
  for (int mt = 0; mt < 8; ++mt)
#pragma unroll
    for (int nt = 0; nt < 4; ++nt) {
      long long col = n0 + wn * 64 + nt * 16 + lr;
#pragma unroll
      for (int r = 0; r < 4; ++r) {
        long long row = m0 + wm * 128 + mt * 16 + lq * 4 + r;
        float v = acc[mt][nt][r];
        if (Cf) Cf[row * N + col] = v;
        else C[row * N + col] = f2b(v);
      }
    }
}

// ---------------- causal flash attention v3 (XCD-remapped grid) ----------
__global__ __launch_bounds__(256, 3) void attn_k(
    const u16* __restrict__ Q, const u16* __restrict__ K,
    const u16* __restrict__ Vt, u16* __restrict__ Y) {
  __shared__ u16 Ks[64 * 128];        // row=key, 16 chunks/row, slot=(g+key)&15
  __shared__ u16 Vs[128 * 64];        // row=d, 8 chunks/row, slot=(g+d)&7
  __shared__ u16 Ps[4][32 * 72];      // per-wave P [q][key], pad 64->72
  __shared__ float Al[4][32];         // per-wave alpha / l broadcast
  // XCD remap (hw xcd = lin%8; gx = NQT/2 = 8): XCD k owns bh in [8k, 8k+8)
  int lin = blockIdx.x + (blockIdx.y << 3);
  int pair = (lin >> 6);              // 0..NQT/2-1
  int bh = ((lin & 7) << 3) + ((lin >> 3) & 7);
  int b = bh >> 4, h = bh & 15;
  int tid = threadIdx.x, lane = tid & 63, wave = tid >> 6;
  int lr = lane & 15, lq = lane >> 4;

  const u16* kp[4];
  const u16* vp[4];
#pragma unroll
  for (int p = 0; p < 4; ++p) {
    int c = p * 256 + wave * 64 + lane;
    int key = c >> 4, sk = c & 15, gk = (sk - key) & 15;
    kp[p] = K + (((long long)b * T_SEQ + key) * NHEAD + h) * HDIM + gk * 8;
    int d = c >> 3, sv = c & 7, gv = (sv - d) & 7;
    vp[p] = Vt + ((long long)bh * HDIM + d) * T_SEQ + gv * 8;
  }

#pragma unroll 1
  for (int phase = 0; phase < 2; ++phase) {
    int qt = phase == 0 ? (NQT - 1 - pair) : pair;
    int qbase = qt * 128 + wave * 32;

    bf16x8 aq[2][4];
#pragma unroll
    for (int n2 = 0; n2 < 2; ++n2) {
      const u16* qp = Q + (((long long)b * T_SEQ + qbase + n2 * 16 + lr) * NHEAD + h) * HDIM;
#pragma unroll
      for (int kt = 0; kt < 4; ++kt)
        aq[n2][kt] = *reinterpret_cast<const bf16x8*>(qp + kt * 32 + lq * 8);
    }

    float m_s[2], l_s[2];
#pragma unroll
    for (int n2 = 0; n2 < 2; ++n2) { m_s[n2] = -INFINITY; l_s[n2] = 0.f; }
    f32x4 o[2][8] = {};

    int niter = 2 * qt + 2;
    for (int j = 0; j < niter; ++j) {
      __syncthreads();
#pragma unroll
      for (int p = 0; p < 4; ++p) {
        __builtin_amdgcn_global_load_lds(
            (g_u32*)(kp[p] + (long long)j * 64 * NHEAD * HDIM),
            (l_u32*)(Ks + p * 2048 + wave * 512), 16, 0, 0);
        __builtin_amdgcn_global_load_lds(
            (g_u32*)(vp[p] + j * 64),
            (l_u32*)(Vs + p * 2048 + wave * 512), 16, 0, 0);
      }
      __syncthreads();

      f32x4 s[4][2];
#pragma unroll
      for (int mt = 0; mt < 4; ++mt) {
        int key = mt * 16 + lr;
        bf16x8 ak[4];
#pragma unroll
        for (int kt = 0; kt < 4; ++kt) {
          int slot = (kt * 4 + lq + key) & 15;
          ak[kt] = *reinterpret_cast<const bf16x8*>(&Ks[key * 128 + slot * 8]);
        }
#pragma unroll
        for (int n2 = 0; n2 < 2; ++n2) {
          f32x4 acc = {};
#pragma unroll
          for (int kt = 0; kt < 4; ++kt)
            acc = __builtin_amdgcn_mfma_f32_16x16x32_bf16(ak[kt], aq[n2][kt], acc, 0, 0, 0);
          s[mt][n2] = acc;
        }
      }

      if (j >= 2 * qt) {
#pragma unroll
        for (int mt = 0; mt < 4; ++mt)
#pragma unroll
          for (int n2 = 0; n2 < 2; ++n2) {
            int q = qbase + n2 * 16 + lr;
#pragma unroll
            for (int r = 0; r < 4; ++r) {
              int key = j * 64 + mt * 16 + lq * 4 + r;
              if (key > q) s[mt][n2][r] = -INFINITY;
            }
          }
      }

      float alpha[2];
#pragma unroll
      for (int n2 = 0; n2 < 2; ++n2) {
        float mx = s[0][n2][0];
#pragma unroll
        for (int mt = 0; mt < 4; ++mt)
#pragma unroll
          for (int r = 0; r < 4; ++r) mx = fmaxf(mx, s[mt][n2][r]);
        mx = fmaxf(mx, __shfl_xor(mx, 16, 64));
        mx = fmaxf(mx, __shfl_xor(mx, 32, 64));
        float mn = fmaxf(m_s[n2], mx);
        alpha[n2] = __expf(m_s[n2] - mn);
        m_s[n2] = mn;
        float sum = 0.f;
        int q = n2 * 16 + lr;
#pragma unroll
        for (int mt = 0; mt < 4; ++mt) {
          ushort4 pk;
          float p0 = __expf(s[mt][n2][0] - mn);
          float p1 = __expf(s[mt][n2][1] - mn);
          float p2 = __expf(s[mt][n2][2] - mn);
          float p3 = __expf(s[mt][n2][3] - mn);
          sum += (p0 + p1) + (p2 + p3);
          pk.x = f2b(p0); pk.y = f2b(p1); pk.z = f2b(p2); pk.w = f2b(p3);
          *reinterpret_cast<ushort4*>(&Ps[wave][q * 72 + mt * 16 + lq * 4]) = pk;
        }
        sum += __shfl_xor(sum, 16, 64);
        sum += __shfl_xor(sum, 32, 64);
        l_s[n2] = l_s[n2] * alpha[n2] + sum;
      }

      if (lq == 0) {
        Al[wave][lr] = alpha[0];
        Al[wave][16 + lr] = alpha[1];
      }
#pragma unroll
      for (int q2 = 0; q2 < 2; ++q2) {
        f32x4 av = *reinterpret_cast<const f32x4*>(&Al[wave][q2 * 16 + lq * 4]);
#pragma unroll
        for (int r = 0; r < 4; ++r)
#pragma unroll
          for (int dt = 0; dt < 8; ++dt) o[q2][dt][r] *= av[r];
      }

#pragma unroll
      for (int kh = 0; kh < 2; ++kh) {
        bf16x8 ap[2];
#pragma unroll
        for (int q2 = 0; q2 < 2; ++q2)
          ap[q2] = *reinterpret_cast<const bf16x8*>(
              &Ps[wave][(q2 * 16 + lr) * 72 + kh * 32 + lq * 8]);
#pragma unroll
        for (int dt = 0; dt < 8; ++dt) {
          int d = dt * 16 + lr;
          int slot = (kh * 4 + lq + d) & 7;
          bf16x8 bv = *reinterpret_cast<const bf16x8*>(&Vs[d * 64 + slot * 8]);
#pragma unroll
          for (int q2 = 0; q2 < 2; ++q2)
            o[q2][dt] = __builtin_amdgcn_mfma_f32_16x16x32_bf16(ap[q2], bv, o[q2][dt], 0, 0, 0);
        }
      }
    }

    if (lq == 0) {
      Al[wave][lr] = l_s[0];
      Al[wave][16 + lr] = l_s[1];
    }
#pragma unroll
    for (int q2 = 0; q2 < 2; ++q2) {
      f32x4 lv = *reinterpret_cast<const f32x4*>(&Al[wave][q2 * 16 + lq * 4]);
#pragma unroll
      for (int r = 0; r < 4; ++r) {
        float inv = 1.0f / lv[r];
        int q = qbase + q2 * 16 + lq * 4 + r;
        u16* yp = Y + (((long long)b * T_SEQ + q) * NHEAD + h) * HDIM;
#pragma unroll
        for (int dt = 0; dt < 8; ++dt)
          yp[dt * 16 + lr] = f2b(o[q2][dt][r] * inv);
      }
    }
  }
}

extern "C" void kernel_launch(void* const* d_in, const int* in_sizes, int n_in,
                              void* d_out, int out_size, void* d_ws, size_t ws_size,
                              hipStream_t stream) {
  (void)in_sizes; (void)n_in; (void)out_size; (void)ws_size;
  const float* x  = (const float*)d_in[0];
  const float* wq = (const float*)d_in[1];
  const float* wk = (const float*)d_in[2];
  const float* wv = (const float*)d_in[3];
  const float* wo = (const float*)d_in[4];
  float* out = (float*)d_out;

  char* ws = (char*)d_ws;
  size_t off = 0;
  auto alloc = [&](size_t bytes) {
    char* p = ws + off;
    off += (bytes + 255) & ~(size_t)255;
    return p;
  };
  const size_t NTOK = (size_t)BATCH * T_SEQ;
  const size_t XE = NTOK * E_DIM;
  const size_t WE = (size_t)E_DIM * E_DIM;

  u16* xb  = (u16*)alloc(XE * 2);
  u16* wqt = (u16*)alloc(WE * 2);
  u16* wkt = (u16*)alloc(WE * 2);
  u16* wvt = (u16*)alloc(WE * 2);
  u16* wot = (u16*)alloc(WE * 2);
  u16* Qb  = (u16*)alloc(XE * 2);
  u16* Kb  = (u16*)alloc(XE * 2);
  u16* Vb  = (u16*)alloc(XE * 2);
  u16* Vt  = (u16*)alloc(XE * 2);
  u16* Yb  = (u16*)alloc(XE * 2);
  float* cost = (float*)alloc((size_t)T_SEQ * 64 * 4);
  float* sint = (float*)alloc((size_t)T_SEQ * 64 * 4);

  convert_f32_bf16<<<XE / 1024, 256, 0, stream>>>(x, xb, (int)XE);
  dim3 gw(E_DIM / 64, E_DIM / 64);
  convt_w_k<<<gw, 256, 0, stream>>>(wq, wqt);
  convt_w_k<<<gw, 256, 0, stream>>>(wk, wkt);
  convt_w_k<<<gw, 256, 0, stream>>>(wv, wvt);
  convt_w_k<<<gw, 256, 0, stream>>>(wo, wot);
  rope_tables_k<<<(T_SEQ * 64) / 256, 256, 0, stream>>>(cost, sint);

  dim3 gq(E_DIM / 256, NTOK / 256, 3);
  gemm_bt_k<<<gq, 512, 0, stream>>>(xb, wqt, wkt, wvt, Qb, Kb, Vb, nullptr,
                                    (int)NTOK, E_DIM, E_DIM);

  rope_rms_k<<<(unsigned)(NTOK * NHEAD / 4) * 2, 256, 0, stream>>>(Qb, Kb, cost, sint);

  dim3 gt(T_SEQ / 64, HDIM / 64, BATCH * NHEAD);
  transpose_v_k<<<gt, 256, 0, stream>>>(Vb, Vt);

  dim3 ga(NQT / 2, BATCH * NHEAD);
  attn_k<<<ga, 256, 0, stream>>>(Qb, Kb, Vt, Yb);

  dim3 go(E_DIM / 256, NTOK / 256, 1);
  gemm_bt_k<<<go, 512, 0, stream>>>(Yb, wot, wot, wot, nullptr, nullptr, nullptr, out,
                                    (int)NTOK, E_DIM, E_DIM);
}

// Round 6
// 571.464 us; speedup vs baseline: 1.3765x; 1.0830x over previous
//
#include <hip/hip_runtime.h>
#include <math.h>

#define T_SEQ 2048
#define BATCH 4
#define E_DIM 2048
#define NHEAD 16
#define HDIM 128
#define RMS_EPS 1.1920929e-07f
#define NQT (T_SEQ / 128)          // 16 q-tiles of 128

typedef unsigned short u16;
typedef __attribute__((ext_vector_type(8))) unsigned short u16x8;
typedef __attribute__((ext_vector_type(8))) short bf16x8;
typedef __attribute__((ext_vector_type(4))) float f32x4;

typedef const __attribute__((address_space(1))) unsigned int g_u32;
typedef __attribute__((address_space(3))) unsigned int l_u32;

static __device__ __forceinline__ u16 f2b(float f) {
  unsigned int u = __builtin_bit_cast(unsigned int, f);
  u += 0x7fffu + ((u >> 16) & 1u);
  return (u16)(u >> 16);
}
static __device__ __forceinline__ float b2f(u16 v) {
  return __builtin_bit_cast(float, ((unsigned int)v) << 16);
}

// ---------------- fp32 -> bf16 convert (x only) ----------------
__global__ __launch_bounds__(256) void convert_f32_bf16(
    const float* __restrict__ src, u16* __restrict__ dst, int n) {
  int i = (blockIdx.x * 256 + threadIdx.x) * 4;
  if (i >= n) return;
  float4 v = *reinterpret_cast<const float4*>(src + i);
  ushort4 o;
  o.x = f2b(v.x); o.y = f2b(v.y); o.z = f2b(v.z); o.w = f2b(v.w);
  *reinterpret_cast<ushort4*>(dst + i) = o;
}

// ---------------- fused fp32->bf16 convert + transpose: Wt[n][k]=W[k][n] ----
__global__ __launch_bounds__(256) void convt_w_k(
    const float* __restrict__ W, u16* __restrict__ Wt) {
  __shared__ u16 tile[64][72];
  int c0 = blockIdx.x * 64;
  int r0 = blockIdx.y * 64;
  int tid = threadIdx.x;
  int lrow = tid >> 2;
  int lcol = (tid & 3) * 16;
#pragma unroll
  for (int i = 0; i < 4; ++i) {
    float4 v = *reinterpret_cast<const float4*>(
        W + (long long)(r0 + lrow) * E_DIM + c0 + lcol + i * 4);
    tile[lrow][lcol + i * 4 + 0] = f2b(v.x);
    tile[lrow][lcol + i * 4 + 1] = f2b(v.y);
    tile[lrow][lcol + i * 4 + 2] = f2b(v.z);
    tile[lrow][lcol + i * 4 + 3] = f2b(v.w);
  }
  __syncthreads();
  int wrow = tid >> 2;
  int wcol = (tid & 3) * 16;
  u16 o[16];
#pragma unroll
  for (int i = 0; i < 16; ++i) o[i] = tile[wcol + i][wrow];
  u16* dst = Wt + (long long)(c0 + wrow) * E_DIM + r0 + wcol;
  *reinterpret_cast<u16x8*>(dst)     = *reinterpret_cast<u16x8*>(&o[0]);
  *reinterpret_cast<u16x8*>(dst + 8) = *reinterpret_cast<u16x8*>(&o[8]);
}

// ---------------- rope tables (double precision trig) ----------------
__global__ __launch_bounds__(256) void rope_tables_k(
    float* __restrict__ cost, float* __restrict__ sint) {
  int idx = blockIdx.x * 256 + threadIdx.x;
  int i = idx & 63, t = idx >> 6;
  double inv = pow(10000.0, -(double)i / 64.0);
  double ang = (double)t * inv;
  cost[idx] = (float)cos(ang);
  sint[idx] = (float)sin(ang);
}

// ---------------- fused rope + rmsnorm (in-place on bf16 Q and K) ----------
__global__ __launch_bounds__(256) void rope_rms_k(
    u16* __restrict__ Qb, u16* __restrict__ Kb, const float* __restrict__ cost,
    const float* __restrict__ sint) {
  int half = gridDim.x >> 1;
  int isK = blockIdx.x >= half;
  u16* qk = isK ? Kb : Qb;
  float outscale = isK ? 1.0f : 0.08838834764831845f;  // fold 1/sqrt(128) into Q
  int wave = threadIdx.x >> 6;
  int lane = threadIdx.x & 63;
  long long row = (long long)(blockIdx.x - (isK ? half : 0)) * 4 + wave;
  int th = (int)(row >> 4);
  int t = th & (T_SEQ - 1);
  u16* p = qk + row * HDIM;
  float x1 = b2f(p[lane]);
  float x2 = b2f(p[lane + 64]);
  float c = cost[t * 64 + lane];
  float s = sint[t * 64 + lane];
  float o1 = x1 * c - x2 * s;
  float o2 = x1 * s + x2 * c;
  float ss = o1 * o1 + o2 * o2;
#pragma unroll
  for (int m = 32; m >= 1; m >>= 1) ss += __shfl_xor(ss, m, 64);
  float r = rsqrtf(ss * (1.0f / 128.0f) + RMS_EPS) * outscale;
  p[lane] = f2b(o1 * r);
  p[lane + 64] = f2b(o2 * r);
}

// ---------------- V transpose: [B,T,H,D] -> per (b,h): [D][T] ----------------
__global__ __launch_bounds__(256) void transpose_v_k(
    const u16* __restrict__ V, u16* __restrict__ Vt) {
  __shared__ u16 tile[64][72];
  int t0 = blockIdx.x * 64, d0 = blockIdx.y * 64;
  int bh = blockIdx.z;
  int b = bh >> 4, h = bh & 15;
  int tid = threadIdx.x;
  int lrow = tid >> 3;
  int lcol = (tid & 7) * 8;
#pragma unroll
  for (int pass = 0; pass < 2; ++pass) {
    int row = lrow + pass * 32;
    const u16* src = V + ((((long long)b * T_SEQ + t0 + row) * NHEAD + h) << 7) + d0 + lcol;
    *reinterpret_cast<u16x8*>(&tile[row][lcol]) = *reinterpret_cast<const u16x8*>(src);
  }
  __syncthreads();
#pragma unroll
  for (int pass = 0; pass < 2; ++pass) {
    int drow = (tid >> 3) + pass * 32;
    int tcol = (tid & 7) * 8;
    u16x8 o;
#pragma unroll
    for (int i = 0; i < 8; ++i) o[i] = tile[tcol + i][drow];
    u16* dst = Vt + ((long long)bh * HDIM + d0 + drow) * T_SEQ + t0 + tcol;
    *reinterpret_cast<u16x8*>(dst) = o;
  }
}

// ---------------- bf16 MFMA GEMM: 256x256 tile, pipelined 4-phase ----------
// (unchanged from R5 -- 195 us, MfmaUtil 46%, 0 bank conflicts)
__global__ __launch_bounds__(512, 2) void gemm_bt_k(
    const u16* __restrict__ A,
    const u16* __restrict__ Bt0, const u16* __restrict__ Bt1, const u16* __restrict__ Bt2,
    u16* __restrict__ C0, u16* __restrict__ C1, u16* __restrict__ C2,
    float* __restrict__ Cf, int M, int N, int K) {
  // ---- XCD-aware tile remap (bijective; gx=8, gy=32, gz in {1,3}) ----
  int lin = blockIdx.x + (blockIdx.y << 3) + (blockIdx.z << 8);
  int kx = lin & 7, ii = lin >> 3;
  int by = ((kx >> 1) << 3) + (ii & 7);   // m-tile: 8-chunk per XCD-pair class
  int bx, bz;
  if (gridDim.z == 3) {
    int u = (kx & 1) * 12 + (ii >> 3);    // 24 (n,z) tiles split in two 12-slices
    bx = u & 7; bz = u >> 3;
  } else {
    bx = ((kx & 1) << 2) + (ii >> 3);     // 8 n-tiles split in two 4-slices
    bz = 0;
  }
  const u16* Bt = bz == 0 ? Bt0 : (bz == 1 ? Bt1 : Bt2);
  u16* C = bz == 0 ? C0 : (bz == 1 ? C1 : C2);

  __shared__ u16 As[2][256 * 64];
  __shared__ u16 Bs[2][256 * 64];
  u16* A0 = As[0]; u16* A1 = As[1];
  u16* B0 = Bs[0]; u16* B1 = Bs[1];
  const int tid = threadIdx.x;
  const int lane = tid & 63, wave = tid >> 6;
  const int wm = wave >> 2, wn = wave & 3;   // 2 x 4 wave grid
  const int m0 = by * 256, n0 = bx * 256;
  const int lr = lane & 15, lq = lane >> 4, l7 = lane & 7;
  const int NT = K >> 6;

  // Staging halves: A half h = rows with bit6==h; B half h = rows bit5==h.
  int rowA[2][2], rowB[2][2];
  const u16* gA[2][2];
  const u16* gB[2][2];
#pragma unroll
  for (int l = 0; l < 2; ++l) {
    int rihb = l * 64 + wave * 8;
#pragma unroll
    for (int h = 0; h < 2; ++h) {
      int ra = ((rihb >> 6) << 7) + h * 64 + (rihb & 63);
      int rb = ((rihb >> 5) << 6) + h * 32 + (rihb & 31);
      rowA[h][l] = ra;
      rowB[h][l] = rb;
      int rA = ra + (lane >> 3);
      int rB = rb + (lane >> 3);
      // inverse-swizzled global source: LDS[r][c] <- G[r][c ^ (r&7)]
      gA[h][l] = A + (long long)(m0 + rA) * K + ((l7 ^ (rA & 7)) * 8);
      gB[h][l] = Bt + (long long)(n0 + rB) * K + ((l7 ^ (rB & 7)) * 8);
    }
  }

  f32x4 acc[8][4] = {};
  bf16x8 aX[2][2], aY[2][2], bB[4][2];

#define GLDS(gp, lp) \
  __builtin_amdgcn_global_load_lds((g_u32*)(gp), (l_u32*)(lp), 16, 0, 0)
#define STG_A(bufp, h, off) do {                                              \
    GLDS(gA[h][0] + (off), (bufp) + rowA[h][0] * 64);                         \
    GLDS(gA[h][1] + (off), (bufp) + rowA[h][1] * 64); } while (0)
#define STG_B(bufp, h, off) do {                                              \
    GLDS(gB[h][0] + (off), (bufp) + rowB[h][0] * 64);                         \
    GLDS(gB[h][1] + (off), (bufp) + rowB[h][1] * 64); } while (0)
#define LDSA(dst, buf, mtb)                                                   \
  _Pragma("unroll") for (int mi = 0; mi < 2; ++mi)                            \
  _Pragma("unroll") for (int ks = 0; ks < 2; ++ks)                            \
    dst[mi][ks] = *reinterpret_cast<const bf16x8*>(                           \
        (buf) + (wm * 128 + ((mtb) + mi) * 16 + lr) * 64 +                    \
        ((((ks) << 2) + lq) ^ l7) * 8);
#define LDSB(dst, buf)                                                        \
  _Pragma("unroll") for (int ni = 0; ni < 4; ++ni)                            \
  _Pragma("unroll") for (int ks = 0; ks < 2; ++ks)                            \
    dst[ni][ks] = *reinterpret_cast<const bf16x8*>(                           \
        (buf) + (wn * 64 + (ni) * 16 + lr) * 64 +                             \
        ((((ks) << 2) + lq) ^ l7) * 8);
#define MFMA2(ph, a)                                                          \
  _Pragma("unroll") for (int mi = 0; mi < 2; ++mi)                            \
  _Pragma("unroll") for (int ni = 0; ni < 4; ++ni)                            \
  _Pragma("unroll") for (int ks = 0; ks < 2; ++ks)                            \
    acc[(ph) * 2 + mi][ni] = __builtin_amdgcn_mfma_f32_16x16x32_bf16(         \
        a[mi][ks], bB[ni][ks], acc[(ph) * 2 + mi][ni], 0, 0, 0);
#define SB __builtin_amdgcn_sched_barrier(0)
#define BAR __builtin_amdgcn_s_barrier()
#define VMC(n) asm volatile("s_waitcnt vmcnt(" #n ")" ::: "memory")
#define PH_MID SB; BAR; SB; __builtin_amdgcn_s_setprio(1)
#define PH_END __builtin_amdgcn_s_setprio(0); SB

  // prologue: tile0 (8 loads) + tile1 {B(1,h0),B(1,h1),A(1,h0)} (6 loads);
  // vmcnt(6) completes tile0, keeps 3 halves in flight; preload fragments.
  GLDS(gB[0][0], B0 + rowB[0][0] * 64); GLDS(gB[0][1], B0 + rowB[0][1] * 64);
  GLDS(gB[1][0], B0 + rowB[1][0] * 64); GLDS(gB[1][1], B0 + rowB[1][1] * 64);
  GLDS(gA[0][0], A0 + rowA[0][0] * 64); GLDS(gA[0][1], A0 + rowA[0][1] * 64);
  GLDS(gA[1][0], A0 + rowA[1][0] * 64); GLDS(gA[1][1], A0 + rowA[1][1] * 64);
  GLDS(gB[0][0] + 64, B1 + rowB[0][0] * 64); GLDS(gB[0][1] + 64, B1 + rowB[0][1] * 64);
  GLDS(gB[1][0] + 64, B1 + rowB[1][0] * 64); GLDS(gB[1][1] + 64, B1 + rowB[1][1] * 64);
  GLDS(gA[0][0] + 64, A1 + rowA[0][0] * 64); GLDS(gA[0][1] + 64, A1 + rowA[0][1] * 64);
  VMC(6);
  BAR; SB;
  LDSB(bB, B0);
  LDSA(aX, A0, 0);
  SB;

#pragma unroll 1
  for (int t = 0; t < NT; t += 2) {
    const bool nl = (t + 2 < NT);       // not last iteration
    // ===== tile t (A regs from A0, bB holds B(t)) =====
    // p1: prefetch aY(mt2,3); stage A(t+1,h1)->A1
    LDSA(aY, A0, 2);
    STG_A(A1, 1, 64);
    PH_MID; MFMA2(0, aX); PH_END;
    // p2: prefetch aX(mt4,5); stage B(t+2,h0)->B0; publish B(t+1)
    LDSA(aX, A0, 4);
    if (nl) { STG_B(B0, 0, 128); VMC(6); } else { VMC(4); }
    PH_MID; MFMA2(1, aY); PH_END;
    // p3: prefetch aY(mt6,7); stage B(t+2,h1)->B0; publish A(t+1)
    LDSA(aY, A0, 6);
    if (nl) { STG_B(B0, 1, 128); VMC(4); } else { VMC(0); }
    PH_MID; MFMA2(2, aX); PH_END;
    // p4: prefetch aX(t+1,mt0,1); stage A(t+2,h0)->A0;
    //     reload bB <- B(t+1) AFTER last use (in-order issue: WAR safe)
    LDSA(aX, A1, 0);
    if (nl) STG_A(A0, 0, 128);
    PH_MID; MFMA2(3, aY);
    LDSB(bB, B1);
    PH_END;
    // ===== tile t+1 (A regs from A1, bB holds B(t+1)) =====
    // p1': prefetch aY; stage A(t+2,h1)->A0
    LDSA(aY, A1, 2);
    if (nl) STG_A(A0, 1, 128);
    PH_MID; MFMA2(0, aX); PH_END;
    // p2': prefetch aX; stage B(t+3,h0)->B1; publish B(t+2)
    LDSA(aX, A1, 4);
    if (nl) { STG_B(B1, 0, 192); VMC(6); }
    PH_MID; MFMA2(1, aY); PH_END;
    // p3': prefetch aY; stage B(t+3,h1)->B1; publish A(t+2)
    LDSA(aY, A1, 6);
    if (nl) { STG_B(B1, 1, 192); VMC(4); }
    PH_MID; MFMA2(2, aX); PH_END;
    // p4': prefetch aX(t+2,mt0,1); stage A(t+3,h0)->A1; reload bB <- B(t+2)
    LDSA(aX, A0, 0);
    if (nl) STG_A(A1, 0, 192);
    PH_MID; MFMA2(3, aY);
    LDSB(bB, B0);
    PH_END;
    // advance 2 K-tiles
#pragma unroll
    for (int l = 0; l < 2; ++l)
#pragma unroll
      for (int h = 0; h < 2; ++h) { gA[h][l] += 128; gB[h][l] += 128; }
  }
#undef LDSA
#undef LDSB
#undef MFMA2
#undef STG_A
#undef STG_B
#undef PH_MID
#undef PH_END

  // epilogue: C col = lane&15, row = (lane>>4)*4 + reg   (16x16 C/D layout)
#pragma unroll
  for (int mt = 0; mt < 8; ++mt)
#pragma unroll
    for (int nt = 0; nt < 4; ++nt) {
      long long col = n0 + wn * 64 + nt * 16 + lr;
#pragma unroll
      for (int r = 0; r < 4; ++r) {
        long long row = m0 + wm * 128 + mt * 16 + lq * 4 + r;
        float v = acc[mt][nt][r];
        if (Cf) Cf[row * N + col] = v;
        else C[row * N + col] = f2b(v);
      }
    }
}

// ---------------- causal flash attention v4: pipelined K/V staging --------
// R6 change: K double-buffered (Ks2[2]), V single-buffered; counted vmcnt
// instead of the per-j full drain.  Per j: QK runs on K(j) staged one full
// iteration earlier; V(j) lands under QK+softmax (vmcnt(4)); K(j+1) lands
// under the whole previous body (vmcnt(8)).  Ledger verified incl. tails:
// V-publish vmcnt(4) -> vmcnt(0) on last iter; K-publish vmcnt(8) ->
// vmcnt(4) when j+2==niter (counts tighten where guards skip issues).
// LDS 68 KB -> 2 blocks/CU (= the 2 blocks/CU of actual work).
__global__ __launch_bounds__(256, 2) void attn_k(
    const u16* __restrict__ Q, const u16* __restrict__ K,
    const u16* __restrict__ Vt, u16* __restrict__ Y) {
  __shared__ u16 Ks2[2][64 * 128];    // row=key, 16 chunks/row, slot=(g+key)&15
  __shared__ u16 Vs[128 * 64];        // row=d, 8 chunks/row, slot=(g+d)&7
  __shared__ u16 Ps[4][32 * 72];      // per-wave P [q][key], pad 64->72
  __shared__ float Al[4][32];         // per-wave alpha / l broadcast
  // XCD remap (hw xcd = lin%8; gx = NQT/2 = 8): XCD k owns bh in [8k, 8k+8)
  int lin = blockIdx.x + (blockIdx.y << 3);
  int pair = (lin >> 6);              // 0..NQT/2-1
  int bh = ((lin & 7) << 3) + ((lin >> 3) & 7);
  int b = bh >> 4, h = bh & 15;
  int tid = threadIdx.x, lane = tid & 63, wave = tid >> 6;
  int lr = lane & 15, lq = lane >> 4;

  const u16* kp[4];
  const u16* vp[4];
#pragma unroll
  for (int p = 0; p < 4; ++p) {
    int c = p * 256 + wave * 64 + lane;
    int key = c >> 4, sk = c & 15, gk = (sk - key) & 15;
    kp[p] = K + (((long long)b * T_SEQ + key) * NHEAD + h) * HDIM + gk * 8;
    int d = c >> 3, sv = c & 7, gv = (sv - d) & 7;
    vp[p] = Vt + ((long long)bh * HDIM + d) * T_SEQ + gv * 8;
  }
  const long long KSTRIDE = (long long)64 * NHEAD * HDIM;

#define AGL(gp, lp) \
  __builtin_amdgcn_global_load_lds((g_u32*)(gp), (l_u32*)(lp), 16, 0, 0)
#define AVMC(n) asm volatile("s_waitcnt vmcnt(" #n ")" ::: "memory")
#define STG_K(j, buf) do { _Pragma("unroll")                                  \
    for (int p = 0; p < 4; ++p)                                               \
      AGL(kp[p] + (long long)(j) * KSTRIDE,                                   \
          Ks2[buf] + p * 2048 + wave * 512); } while (0)
#define STG_V(j) do { _Pragma("unroll")                                       \
    for (int p = 0; p < 4; ++p)                                               \
      AGL(vp[p] + (j) * 64, Vs + p * 2048 + wave * 512); } while (0)

#pragma unroll 1
  for (int phase = 0; phase < 2; ++phase) {
    int qt = phase == 0 ? (NQT - 1 - pair) : pair;
    int qbase = qt * 128 + wave * 32;
    int niter = 2 * qt + 2;

    bf16x8 aq[2][4];
#pragma unroll
    for (int n2 = 0; n2 < 2; ++n2) {
      const u16* qp = Q + (((long long)b * T_SEQ + qbase + n2 * 16 + lr) * NHEAD + h) * HDIM;
#pragma unroll
      for (int kt = 0; kt < 4; ++kt)
        aq[n2][kt] = *reinterpret_cast<const bf16x8*>(qp + kt * 32 + lq * 8);
    }

    float m_s[2], l_s[2];
#pragma unroll
    for (int n2 = 0; n2 < 2; ++n2) { m_s[n2] = -INFINITY; l_s[n2] = 0.f; }
    f32x4 o[2][8] = {};

    // prologue: K(0) published; V(0) + K(1) launched (invariant for j=0)
    STG_K(0, 0);
    AVMC(0);
    __builtin_amdgcn_s_barrier();
    STG_V(0);
    STG_K(1, 1);                       // niter >= 2 always

#pragma unroll 1
    for (int j = 0; j < niter; ++j) {
      const u16* Kb = Ks2[j & 1];

      f32x4 s[4][2];
#pragma unroll
      for (int mt = 0; mt < 4; ++mt) {
        int key = mt * 16 + lr;
        bf16x8 ak[4];
#pragma unroll
        for (int kt = 0; kt < 4; ++kt) {
          int slot = (kt * 4 + lq + key) & 15;
          ak[kt] = *reinterpret_cast<const bf16x8*>(&Kb[key * 128 + slot * 8]);
        }
#pragma unroll
        for (int n2 = 0; n2 < 2; ++n2) {
          f32x4 acc = {};
#pragma unroll
          for (int kt = 0; kt < 4; ++kt)
            acc = __builtin_amdgcn_mfma_f32_16x16x32_bf16(ak[kt], aq[n2][kt], acc, 0, 0, 0);
          s[mt][n2] = acc;
        }
      }

      if (j >= 2 * qt) {
#pragma unroll
        for (int mt = 0; mt < 4; ++mt)
#pragma unroll
          for (int n2 = 0; n2 < 2; ++n2) {
            int q = qbase + n2 * 16 + lr;
#pragma unroll
            for (int r = 0; r < 4; ++r) {
              int key = j * 64 + mt * 16 + lq * 4 + r;
              if (key > q) s[mt][n2][r] = -INFINITY;
            }
          }
      }

      float alpha[2];
#pragma unroll
      for (int n2 = 0; n2 < 2; ++n2) {
        float mx = s[0][n2][0];
#pragma unroll
        for (int mt = 0; mt < 4; ++mt)
#pragma unroll
          for (int r = 0; r < 4; ++r) mx = fmaxf(mx, s[mt][n2][r]);
        mx = fmaxf(mx, __shfl_xor(mx, 16, 64));
        mx = fmaxf(mx, __shfl_xor(mx, 32, 64));
        float mn = fmaxf(m_s[n2], mx);
        alpha[n2] = __expf(m_s[n2] - mn);
        m_s[n2] = mn;
        float sum = 0.f;
        int q = n2 * 16 + lr;
#pragma unroll
        for (int mt = 0; mt < 4; ++mt) {
          ushort4 pk;
          float p0 = __expf(s[mt][n2][0] - mn);
          float p1 = __expf(s[mt][n2][1] - mn);
          float p2 = __expf(s[mt][n2][2] - mn);
          float p3 = __expf(s[mt][n2][3] - mn);
          sum += (p0 + p1) + (p2 + p3);
          pk.x = f2b(p0); pk.y = f2b(p1); pk.z = f2b(p2); pk.w = f2b(p3);
          *reinterpret_cast<ushort4*>(&Ps[wave][q * 72 + mt * 16 + lq * 4]) = pk;
        }
        sum += __shfl_xor(sum, 16, 64);
        sum += __shfl_xor(sum, 32, 64);
        l_s[n2] = l_s[n2] * alpha[n2] + sum;
      }

      if (lq == 0) {
        Al[wave][lr] = alpha[0];
        Al[wave][16 + lr] = alpha[1];
      }
#pragma unroll
      for (int q2 = 0; q2 < 2; ++q2) {
        f32x4 av = *reinterpret_cast<const f32x4*>(&Al[wave][q2 * 16 + lq * 4]);
#pragma unroll
        for (int r = 0; r < 4; ++r)
#pragma unroll
          for (int dt = 0; dt < 8; ++dt) o[q2][dt][r] *= av[r];
      }

      // publish V(j): everything newer is K(j+1) (4 loads) if it exists
      if (j + 1 < niter) { AVMC(4); } else { AVMC(0); }
      __builtin_amdgcn_s_barrier();                      // [B2] V visible

#pragma unroll
      for (int kh = 0; kh < 2; ++kh) {
        bf16x8 ap[2];
#pragma unroll
        for (int q2 = 0; q2 < 2; ++q2)
          ap[q2] = *reinterpret_cast<const bf16x8*>(
              &Ps[wave][(q2 * 16 + lr) * 72 + kh * 32 + lq * 8]);
#pragma unroll
        for (int dt = 0; dt < 8; ++dt) {
          int d = dt * 16 + lr;
          int slot = (kh * 4 + lq + d) & 7;
          bf16x8 bv = *reinterpret_cast<const bf16x8*>(&Vs[d * 64 + slot * 8]);
#pragma unroll
          for (int q2 = 0; q2 < 2; ++q2)
            o[q2][dt] = __builtin_amdgcn_mfma_f32_16x16x32_bf16(ap[q2], bv, o[q2][dt], 0, 0, 0);
        }
      }

      if (j + 1 < niter) {
        __builtin_amdgcn_s_barrier();                    // [B3] close PV reads
        STG_V(j + 1);                                    // Vs free for V(j+1)
        if (j + 2 < niter) {
          STG_K(j + 2, j & 1);                           // K(j) buffer free
          AVMC(8);                                       // K(j+1) landed
        } else {
          AVMC(4);                                       // K(j+1) landed
        }
        __builtin_amdgcn_s_barrier();                    // [B1] K(j+1) visible
      }
    }

    if (lq == 0) {
      Al[wave][lr] = l_s[0];
      Al[wave][16 + lr] = l_s[1];
    }
#pragma unroll
    for (int q2 = 0; q2 < 2; ++q2) {
      f32x4 lv = *reinterpret_cast<const f32x4*>(&Al[wave][q2 * 16 + lq * 4]);
#pragma unroll
      for (int r = 0; r < 4; ++r) {
        float inv = 1.0f / lv[r];
        int q = qbase + q2 * 16 + lq * 4 + r;
        u16* yp = Y + (((long long)b * T_SEQ + q) * NHEAD + h) * HDIM;
#pragma unroll
        for (int dt = 0; dt < 8; ++dt)
          yp[dt * 16 + lr] = f2b(o[q2][dt][r] * inv);
      }
    }
  }
#undef STG_K
#undef STG_V
#undef AGL
#undef AVMC
}

extern "C" void kernel_launch(void* const* d_in, const int* in_sizes, int n_in,
                              void* d_out, int out_size, void* d_ws, size_t ws_size,
                              hipStream_t stream) {
  (void)in_sizes; (void)n_in; (void)out_size; (void)ws_size;
  const float* x  = (const float*)d_in[0];
  const float* wq = (const float*)d_in[1];
  const float* wk = (const float*)d_in[2];
  const float* wv = (const float*)d_in[3];
  const float* wo = (const float*)d_in[4];
  float* out = (float*)d_out;

  char* ws = (char*)d_ws;
  size_t off = 0;
  auto alloc = [&](size_t bytes) {
    char* p = ws + off;
    off += (bytes + 255) & ~(size_t)255;
    return p;
  };
  const size_t NTOK = (size_t)BATCH * T_SEQ;
  const size_t XE = NTOK * E_DIM;
  const size_t WE = (size_t)E_DIM * E_DIM;

  u16* xb  = (u16*)alloc(XE * 2);
  u16* wqt = (u16*)alloc(WE * 2);
  u16* wkt = (u16*)alloc(WE * 2);
  u16* wvt = (u16*)alloc(WE * 2);
  u16* wot = (u16*)alloc(WE * 2);
  u16* Qb  = (u16*)alloc(XE * 2);
  u16* Kb  = (u16*)alloc(XE * 2);
  u16* Vb  = (u16*)alloc(XE * 2);
  u16* Vt  = (u16*)alloc(XE * 2);
  u16* Yb  = (u16*)alloc(XE * 2);
  float* cost = (float*)alloc((size_t)T_SEQ * 64 * 4);
  float* sint = (float*)alloc((size_t)T_SEQ * 64 * 4);

  convert_f32_bf16<<<XE / 1024, 256, 0, stream>>>(x, xb, (int)XE);
  dim3 gw(E_DIM / 64, E_DIM / 64);
  convt_w_k<<<gw, 256, 0, stream>>>(wq, wqt);
  convt_w_k<<<gw, 256, 0, stream>>>(wk, wkt);
  convt_w_k<<<gw, 256, 0, stream>>>(wv, wvt);
  convt_w_k<<<gw, 256, 0, stream>>>(wo, wot);
  rope_tables_k<<<(T_SEQ * 64) / 256, 256, 0, stream>>>(cost, sint);

  dim3 gq(E_DIM / 256, NTOK / 256, 3);
  gemm_bt_k<<<gq, 512, 0, stream>>>(xb, wqt, wkt, wvt, Qb, Kb, Vb, nullptr,
                                    (int)NTOK, E_DIM, E_DIM);

  rope_rms_k<<<(unsigned)(NTOK * NHEAD / 4) * 2, 256, 0, stream>>>(Qb, Kb, cost, sint);

  dim3 gt(T_SEQ / 64, HDIM / 64, BATCH * NHEAD);
  transpose_v_k<<<gt, 256, 0, stream>>>(Vb, Vt);

  dim3 ga(NQT / 2, BATCH * NHEAD);
  attn_k<<<ga, 256, 0, stream>>>(Qb, Kb, Vt, Yb);

  dim3 go(E_DIM / 256, NTOK / 256, 1);
  gemm_bt_k<<<go, 512, 0, stream>>>(Yb, wot, wot, wot, nullptr, nullptr, nullptr, out,
                                    (int)NTOK, E_DIM, E_DIM);
}